// Round 10
// baseline (2513.533 us; speedup 1.0000x reference)
//
#include <hip/hip_runtime.h>
#include <hip/hip_bf16.h>
#include <stdint.h>

typedef unsigned short u16;
typedef unsigned int   u32;
typedef unsigned long long u64;
typedef float v2f __attribute__((ext_vector_type(2)));
typedef __attribute__((ext_vector_type(8))) short bf16x8;
typedef __attribute__((ext_vector_type(4))) float f32x4;

#define B_    8
#define N_    8192
#define M_    2048
#define NS_   32
#define CIN_  64
#define ROWS_ (B_*M_*NS_)          // 524288
#define BIGF  1e10f
#define EPSF  1e-5f
#define INV_ROWS (1.0f/524288.0f)  // 2^-19, exact

__device__ __forceinline__ u16 f2bf(float f){
  u32 x=__float_as_uint(f);
  return (u16)((x + 0x7FFFu + ((x>>16)&1u))>>16);   // RNE
}
__device__ __forceinline__ float bf2f(u16 u){ return __uint_as_float(((u32)u)<<16); }

// ---- packed f32 (VOP3P, both sources aligned VGPR pairs; verified R4 run) ----
__device__ __forceinline__ v2f pk_add(v2f a, v2f b){
  v2f r; asm("v_pk_add_f32 %0, %1, %2" : "=v"(r) : "v"(a), "v"(b)); return r; }
__device__ __forceinline__ v2f pk_mul(v2f a, v2f b){
  v2f r; asm("v_pk_mul_f32 %0, %1, %2" : "=v"(r) : "v"(a), "v"(b)); return r; }

// DPP full-wave max of non-negative u64 keys; result lands in lane 63.
__device__ __forceinline__ u64 wave_max_key(u64 k){
#define DPP_LVL(CTRL) { \
    u32 lo_=(u32)__builtin_amdgcn_update_dpp(0,(int)(u32)k,(CTRL),0xF,0xF,true); \
    u32 hi_=(u32)__builtin_amdgcn_update_dpp(0,(int)(u32)(k>>32),(CTRL),0xF,0xF,true); \
    u64 o_=((u64)hi_<<32)|(u64)lo_; \
    k=(o_>k)?o_:k; }
  DPP_LVL(0x111)  // row_shr:1
  DPP_LVL(0x112)  // row_shr:2
  DPP_LVL(0x114)  // row_shr:4
  DPP_LVL(0x118)  // row_shr:8
  DPP_LVL(0x142)  // row_bcast:15
  DPP_LVL(0x143)  // row_bcast:31  -> lane 63 holds wave max
#undef DPP_LVL
  return k;
}

// ---------------------------------------------------------------- prep (fp32 weights in)
// B-frag layout (16x16x32): col = tn*16 + (lane&15), k = k0*32 + ((lane>>4)&3)*8 + e.
// Split precision: w = bf16(hi) + bf16(w - hi)  (~2^-17 rel error).
// W0 fragments use the STAGED channel order: k<64 -> feat ch (w0 col 3+k),
// 64<=k<67 -> xyz ch (w0 col k-64), k>=67 -> 0. (3 K-steps, padded to 96.)
__global__ __launch_bounds__(256) void k_prep(
    const float* w0,const float* b0,const float* g0,const float* bt0,
    const float* w1,const float* b1,const float* g1,const float* bt1,
    const float* w2,const float* b2,const float* g2,const float* bt2,
    float* biasf,float* gf,float* btf,float* stats,
    u16* Wb0h, u16* Wb0l, u16* Wb1h, u16* Wb1l, u16* Wb2h, u16* Wb2l)
{
  int tid=threadIdx.x;
  for (int i=tid;i<768;i+=256) stats[i]=0.f;
  // W0 B-fragments (64 out cols -> tn 0..3, 3 k-steps)
  for (int i=tid;i<6144;i+=256){
    int e=i&7, lane=(i>>3)&63, idx=i>>9;        // idx = tn*3 + k0
    int tn=idx/3, k0=idx%3;
    int col = tn*16 + (lane&15);
    int k   = k0*32 + ((lane>>4)&3)*8 + e;      // 0..95
    float v = 0.f;
    if (k < 64)            v = w0[col*67 + 3 + k];
    else if (k < 67)       v = w0[col*67 + (k-64)];
    u16 hib = f2bf(v);
    Wb0h[i] = hib;
    Wb0l[i] = f2bf(v - bf2f(hib));
  }
  // W1 B-fragments (64 cols -> tn 0..3)
  for (int i=tid;i<4096;i+=256){
    int e=i&7, lane=(i>>3)&63, k0=(i>>9)&1, tn=i>>10;
    int col = tn*16 + (lane&15);
    int k   = k0*32 + ((lane>>4)&3)*8 + e;
    float v = w1[col*64 + k];
    u16 hib = f2bf(v);
    Wb1h[i] = hib;
    Wb1l[i] = f2bf(v - bf2f(hib));
  }
  // W2 B-fragments (128 cols -> tn 0..7)
  for (int i=tid;i<8192;i+=256){
    int e=i&7, lane=(i>>3)&63, k0=(i>>9)&1, tn=i>>10;
    int col = tn*16 + (lane&15);
    int k   = k0*32 + ((lane>>4)&3)*8 + e;
    float v = w2[col*64 + k];
    u16 hib = f2bf(v);
    Wb2h[i] = hib;
    Wb2l[i] = f2bf(v - bf2f(hib));
  }
  if (tid<64){
    biasf[0*128+tid]=b0[tid]; gf[0*128+tid]=g0[tid]; btf[0*128+tid]=bt0[tid];
    biasf[1*128+tid]=b1[tid]; gf[1*128+tid]=g1[tid]; btf[1*128+tid]=bt1[tid];
  }
  if (tid<128){
    biasf[2*128+tid]=b2[tid]; gf[2*128+tid]=g2[tid]; btf[2*128+tid]=bt2[tid];
  }
}

// ------------------------------------------------------- feature transpose
__global__ __launch_bounds__(256) void k_tr(const float* __restrict__ feats, u16* __restrict__ featT)
{
  __shared__ float t[64][65];
  int bb=blockIdx.y, n0=blockIdx.x*64, tid=threadIdx.x;
  int a=tid&63, q=tid>>6;
  const float* fp = feats + (size_t)bb*CIN_*N_;
  #pragma unroll
  for (int s=0;s<16;s++){ int c=q*16+s; t[c][a]=fp[(size_t)c*N_ + n0 + a]; }
  __syncthreads();
  u16* op = featT + (size_t)bb*N_*CIN_;
  #pragma unroll
  for (int s=0;s<16;s++){ int n=q*16+s; op[(size_t)(n0+n)*CIN_ + a] = f2bf(t[a][n]); }
}

// ---------------------------------------------------------------- FPS
// R1/R7 proven skeleton (1733us measured: staging, PRE-update emission, in-loop
// u64 keys, single u64 DPP ladder, parity skey[2][8] + 8-load tree merge),
// with ONE change: distance arithmetic forced to packed VOP3P pk_add/pk_mul
// (bit-exact: a+(-c)==a-c in IEEE; pk ops verified in R4's passing run).
// R9 sort/prune REVERTED: prune fired (VALUBusy -45%) but time unchanged --
// barrier pacing means only all-wave issue cuts help, not conditional skips.
__global__ __launch_bounds__(512) void k_fps(const float* __restrict__ xyz,
                                             float* __restrict__ nxyz, float* __restrict__ out0)
{
#pragma clang fp contract(off)
  __shared__ float sx[N_], sy[N_], sz[N_];
  __shared__ int sidx[M_];
  __shared__ u64 skey[2][8];
  int b=blockIdx.x, tid=threadIdx.x;
  const float* xp = xyz + (size_t)b*N_*3;
  for (int i=tid;i<N_;i+=512){ sx[i]=xp[i*3]; sy[i]=xp[i*3+1]; sz[i]=xp[i*3+2]; }
  __syncthreads();
  v2f px[8],py[8],pz[8],md[8];
  int base = tid*16;
  #pragma unroll
  for (int p=0;p<8;p++){
    px[p]=*(const v2f*)&sx[base+2*p];
    py[p]=*(const v2f*)&sy[base+2*p];
    pz[p]=*(const v2f*)&sz[base+2*p];
    v2f m0; m0[0]=BIGF; m0[1]=BIGF; md[p]=m0;
  }
  u32 invb = 0xFFFFFFFFu - (u32)base;
  int far=0;
  int lane=tid&63, wv=tid>>6;
  for (int step=0; step<M_; step++){
    if (tid==0) sidx[step]=far;          // PRE-update emission
    float cxs=sx[far], cys=sy[far], czs=sz[far];
    v2f ncx; ncx[0]=-cxs; ncx[1]=-cxs;   // splat -centroid (a-c == a+(-c), exact)
    v2f ncy; ncy[0]=-cys; ncy[1]=-cys;
    v2f ncz; ncz[0]=-czs; ncz[1]=-czs;
    u64 kb=0;
    #pragma unroll
    for (int p=0;p<8;p++){
      v2f dx=pk_add(px[p],ncx);
      v2f dy=pk_add(py[p],ncy);
      v2f dz=pk_add(pz[p],ncz);
      v2f d = pk_add(pk_add(pk_mul(dx,dx), pk_mul(dy,dy)), pk_mul(dz,dz));
      v2f m=__builtin_elementwise_min(md[p],d);
      md[p]=m;
      u64 k0=((u64)__float_as_uint(m[0])<<32)|(u64)(invb-(u32)(2*p));
      u64 k1=((u64)__float_as_uint(m[1])<<32)|(u64)(invb-(u32)(2*p+1));
      u64 kp=(k1>k0)?k1:k0;              // equal dist -> k0 (lower idx) wins: larger ~idx
      kb=(kp>kb)?kp:kb;
    }
    kb = wave_max_key(kb);
    int par = step & 1;
    if (lane==63) skey[par][wv]=kb;
    __syncthreads();                     // single barrier per step
    u64 a0=skey[par][0],a1=skey[par][1],a2=skey[par][2],a3=skey[par][3];
    u64 a4=skey[par][4],a5=skey[par][5],a6=skey[par][6],a7=skey[par][7];
    a0=(a1>a0)?a1:a0; a2=(a3>a2)?a3:a2; a4=(a5>a4)?a5:a4; a6=(a7>a6)?a7:a6;
    a0=(a2>a0)?a2:a0; a4=(a6>a4)?a6:a4;
    a0=(a4>a0)?a4:a0;
    far = (int)(0xFFFFFFFFu - (u32)(a0 & 0xFFFFFFFFull));
  }
  // f32 output: exact raw coordinates of selected points
  for (int i=tid;i<M_;i+=512){
    int id = sidx[i];
    float x=sx[id], y=sy[id], z=sz[id];
    size_t o=(size_t)(b*M_+i)*3;
    nxyz[o]=x; nxyz[o+1]=y; nxyz[o+2]=z;
    out0[o]=x; out0[o+1]=y; out0[o+2]=z;
  }
}

// ---------------------------------------------------------------- ball query
#define BQCAP 512
__global__ __launch_bounds__(512) void k_bq(const float* __restrict__ xyz, const float* __restrict__ nxyz,
                                            int* __restrict__ knn)
{
  __shared__ float4 sP[N_];
  __shared__ float candd[8][BQCAP];
  __shared__ u16  candi[8][BQCAP];
  int tid=threadIdx.x;
  int cid0 = blockIdx.x*8;
  int b = cid0 >> 11;
  const float* xp = xyz + (size_t)b*N_*3;
  for (int i=tid;i<N_;i+=512){
    float x=xp[i*3], y=xp[i*3+1], z=xp[i*3+2];
    float x2 = __fmul_rn(x,x);
    x2 = __fadd_rn(x2, __fmul_rn(y,y));
    x2 = __fadd_rn(x2, __fmul_rn(z,z));
    sP[i]=make_float4(x,y,z,x2);
  }
  __syncthreads();
  int w=tid>>6, lane=tid&63;
  int cid = cid0 + w;
  float cx=nxyz[(size_t)cid*3], cy=nxyz[(size_t)cid*3+1], cz=nxyz[(size_t)cid*3+2];
  float c2 = __fmul_rn(cx,cx);
  c2 = __fadd_rn(c2, __fmul_rn(cy,cy));
  c2 = __fadd_rn(c2, __fmul_rn(cz,cz));
  int cnt=0;
  for (int i0=0;i0<N_;i0+=64){
    int i=i0+lane;
    float4 p=sP[i];
    float dot = __fmul_rn(cx,p.x);
    dot = __fadd_rn(dot, __fmul_rn(cy,p.y));
    dot = __fadd_rn(dot, __fmul_rn(cz,p.z));
    float d2 = __fsub_rn(__fadd_rn(c2,p.w), __fmul_rn(2.0f,dot));
    float d = sqrtf(fmaxf(d2,0.f));
    bool in = (d <= 0.4f);
    u64 msk = __ballot(in);
    int pos = cnt + __popcll(msk & ((1ull<<lane)-1ull));
    if (in && pos<BQCAP){ candd[w][pos]=d; candi[w][pos]=(u16)i; }
    cnt += __popcll(msk);
  }
  int R = cnt<BQCAP ? cnt : BQCAP;
  int* kout = knn + (size_t)cid*NS_;
  if (R >= NS_){
    for (int s=0;s<NS_;s++){
      u64 kb = ~0ull;                    // min identity
      for (int j=lane;j<R;j+=64){
        float v=candd[w][j];
        u64 k = ((u64)__float_as_uint(v)<<32) | (u64)(u32)j;
        kb = (k<kb)?k:kb;
      }
      u64 inv = wave_max_key(~kb);       // min via complemented max
      if (lane==63){
        u64 kw = ~inv;
        int bpp = (int)(u32)(kw & 0xFFFFFFFFull);
        kout[s]=candi[w][bpp];
        candd[w][bpp]=3e38f;             // same-wave DS in-order: visible next pass
      }
    }
  } else {
    if (lane<R) kout[lane]=candi[w][lane];
    int need = NS_-R, slot = R;
    for (int i0=0; i0<N_ && need>0; i0+=64){
      int i=i0+lane;
      float4 p=sP[i];
      float dot = __fmul_rn(cx,p.x);
      dot = __fadd_rn(dot, __fmul_rn(cy,p.y));
      dot = __fadd_rn(dot, __fmul_rn(cz,p.z));
      float d2 = __fsub_rn(__fadd_rn(c2,p.w), __fmul_rn(2.0f,dot));
      float d = sqrtf(fmaxf(d2,0.f));
      bool in = (d <= 0.4f);
      u64 mm = __ballot(!in);
      while (mm && need>0){
        int bpos = __ffsll((long long)mm)-1;
        if (lane==0) kout[slot] = i0+bpos;
        slot++; need--;
        mm &= mm-1;
      }
    }
  }
}

// ---------------------------------------------------------------- layer 0: MFMA (gather+concat fused)
__global__ __launch_bounds__(256) void k_mm0(const float* __restrict__ xyz, const u16* __restrict__ featT,
                                             const int* __restrict__ knn, const float* __restrict__ nxyz,
                                             const u16* __restrict__ Wb0h, const u16* __restrict__ Wb0l,
                                             const float* __restrict__ bias0, u16* __restrict__ Y0)
{
  __shared__ u16 Xs[64*128];     // 16KB, row stride 256B, swizzled
  __shared__ u16 WH[12*64*8];    // 12KB [tn*3+k0][lane][e]
  __shared__ u16 WL[12*64*8];    // 12KB
  int tid=threadIdx.x;
  {
    const uint4* s4=(const uint4*)Wb0h; uint4* d4=(uint4*)WH;
    const uint4* s5=(const uint4*)Wb0l; uint4* d5=(uint4*)WL;
    for (int i=tid;i<768;i+=256){ d4[i]=s4[i]; d5[i]=s5[i]; }
  }
  size_t base=(size_t)blockIdx.x*64;
  {
    int rl=tid>>2, t=tid&3;                 // 4 threads per row
    int row=(int)base+rl;
    int bm = row>>5, b = row>>16;
    int n  = knn[row];
    const uint4* fp = (const uint4*)(featT + ((size_t)b*N_ + n)*CIN_);
    char* xr = (char*)Xs + rl*256;
    u32 swz = (u32)((rl&7)<<4);
    uint4 v0=fp[t*2], v1=fp[t*2+1];
    *(uint4*)(xr + ((t*32)    ^ swz)) = v0;
    *(uint4*)(xr + ((t*32+16) ^ swz)) = v1;
    uint4 pz = make_uint4(0u,0u,0u,0u);
    if (t==0){
      const float* cp = nxyz + (size_t)bm*3;
      const float* xp = xyz + ((size_t)b*N_ + n)*3;
      u32 w01 = (u32)f2bf(xp[0]-cp[0]) | ((u32)f2bf(xp[1]-cp[1])<<16);
      u32 w2  = (u32)f2bf(xp[2]-cp[2]);
      pz.x = w01; pz.y = w2;
    }
    *(uint4*)(xr + ((128+t*16) ^ swz)) = pz;
  }
  __syncthreads();
  int w=tid>>6, lane=tid&63;
  f32x4 acc[4];
  #pragma unroll
  for (int tn=0;tn<4;tn++){ acc[tn][0]=0.f; acc[tn][1]=0.f; acc[tn][2]=0.f; acc[tn][3]=0.f; }
  int arow = w*16 + (lane&15);
  u32 aswz = (u32)((arow&7)<<4);
  #pragma unroll
  for (int k0=0;k0<3;k0++){
    int aoff = arow*256 + (int)(((u32)((k0*32 + ((lane>>4)&3)*8)*2)) ^ aswz);
    bf16x8 a = *(const bf16x8*)((const char*)Xs + aoff);
    #pragma unroll
    for (int tn=0;tn<4;tn++){
      bf16x8 bl = *(const bf16x8*)&WL[((tn*3+k0)*64+lane)*8];
      bf16x8 bh = *(const bf16x8*)&WH[((tn*3+k0)*64+lane)*8];
      acc[tn] = __builtin_amdgcn_mfma_f32_16x16x32_bf16(a, bl, acc[tn], 0,0,0);
      acc[tn] = __builtin_amdgcn_mfma_f32_16x16x32_bf16(a, bh, acc[tn], 0,0,0);
    }
  }
  #pragma unroll
  for (int tn=0;tn<4;tn++){
    int col = tn*16 + (lane&15);
    float bb = bias0[col];
    #pragma unroll
    for (int j=0;j<4;j++){
      int row = w*16 + (lane>>4)*4 + j;
      Y0[(base+row)*64 + col] = f2bf(acc[tn][j] + bb);
    }
  }
}

// ---------------------------------------------------------------- channel stats (sum, sumsq)
template<int C>
__global__ __launch_bounds__(256) void k_stats(const u16* __restrict__ Y, float* __restrict__ statsOut)
{
  __shared__ float sred[4][128];
  int tid=threadIdx.x;
  int c0=(tid&7)*8;          // 8 channels per thread
  int rg=tid>>3;             // 32 row-groups per block
  float s[8], ss[8];
  #pragma unroll
  for (int k=0;k<8;k++){ s[k]=0.f; ss[k]=0.f; }
  for (size_t r=(size_t)blockIdx.x*32+rg; r<ROWS_; r+=(size_t)gridDim.x*32){
    uint4 v=*(const uint4*)&Y[r*64+c0];
    u32 a[4]={v.x,v.y,v.z,v.w};
    #pragma unroll
    for (int q=0;q<4;q++){
      float lo=bf2f((u16)(a[q]&0xFFFFu));
      float hi=bf2f((u16)(a[q]>>16));
      s[q*2]+=lo;   ss[q*2]+=lo*lo;
      s[q*2+1]+=hi; ss[q*2+1]+=hi*hi;
    }
  }
  #pragma unroll
  for (int off=32; off>=8; off>>=1){
    #pragma unroll
    for (int k=0;k<8;k++){
      s[k]+=__shfl_down(s[k],off);
      ss[k]+=__shfl_down(ss[k],off);
    }
  }
  int lane=tid&63, wv=tid>>6;
  if (lane<8){
    #pragma unroll
    for (int k=0;k<8;k++){
      int ch=lane*8+k;
      sred[wv][ch]=s[k];
      sred[wv][64+ch]=ss[k];
    }
  }
  __syncthreads();
  if (tid<128){
    float a=sred[0][tid]+sred[1][tid]+sred[2][tid]+sred[3][tid];
    int ch=tid&63, which=tid>>6;
    atomicAdd(&statsOut[ch*2+which], a);
  }
}

// ---------------------------------------------------------------- layer 1: MFMA (proven R5)
__global__ __launch_bounds__(256) void k_mm1(u16* __restrict__ Y,
                                             const u16* __restrict__ Wb1h, const u16* __restrict__ Wb1l,
                                             const float* __restrict__ bias1, const float* __restrict__ gf0,
                                             const float* __restrict__ btf0, const float* __restrict__ stats0)
{
  __shared__ u16 Xs[64*64];      // 8KB, swizzled
  __shared__ u16 WH[8*64*8];     // 8KB  [tn*2+k0][lane][e]
  __shared__ u16 WL[8*64*8];     // 8KB
  __shared__ float sc[64], sh[64];
  int tid=threadIdx.x;
  if (tid<64){
    float mu = stats0[tid*2]*INV_ROWS;
    float var= stats0[tid*2+1]*INV_ROWS - mu*mu;
    float rs = 1.0f/sqrtf(var+EPSF);
    float s  = rs*gf0[tid];
    sc[tid]=s; sh[tid]=btf0[tid]-mu*s;
  }
  {
    const uint4* sh4=(const uint4*)Wb1h; uint4* dh4=(uint4*)WH;
    const uint4* sl4=(const uint4*)Wb1l; uint4* dl4=(uint4*)WL;
    dh4[tid]=sh4[tid]; dh4[tid+256]=sh4[tid+256];
    dl4[tid]=sl4[tid]; dl4[tid+256]=sl4[tid+256];
  }
  __syncthreads();
  size_t base=(size_t)blockIdx.x*64;
  for (int i=tid;i<512;i+=256){
    int rl=i>>3, c0=(i&7)*8;
    uint4 v=*(const uint4*)(Y + (base+rl)*64 + c0);
    u32 arr[4]={v.x,v.y,v.z,v.w};
    u32 pk[4];
    #pragma unroll
    for (int q=0;q<4;q++){
      int cc=c0+q*2;
      float lo=bf2f((u16)(arr[q]&0xFFFFu));
      float hi=bf2f((u16)(arr[q]>>16));
      lo=fmaxf(0.f, lo*sc[cc]+sh[cc]);
      hi=fmaxf(0.f, hi*sc[cc+1]+sh[cc+1]);
      pk[q] = (u32)f2bf(lo) | ((u32)f2bf(hi)<<16);
    }
    uint4 o4; o4.x=pk[0]; o4.y=pk[1]; o4.z=pk[2]; o4.w=pk[3];
    int byteoff = rl*128 + ((c0*2) ^ ((rl&7)<<4));
    *(uint4*)((char*)Xs + byteoff) = o4;
  }
  __syncthreads();
  int w=tid>>6, lane=tid&63;
  f32x4 acc[4];
  #pragma unroll
  for (int tn=0;tn<4;tn++){ acc[tn][0]=0.f; acc[tn][1]=0.f; acc[tn][2]=0.f; acc[tn][3]=0.f; }
  int arow = w*16 + (lane&15);
  #pragma unroll
  for (int k0=0;k0<2;k0++){
    int aoff = arow*128 + ((k0*64 + (lane>>4)*16) ^ ((arow&7)<<4));
    bf16x8 a = *(const bf16x8*)((const char*)Xs + aoff);
    #pragma unroll
    for (int tn=0;tn<4;tn++){
      bf16x8 bl = *(const bf16x8*)&WL[((tn*2+k0)*64+lane)*8];
      bf16x8 bh = *(const bf16x8*)&WH[((tn*2+k0)*64+lane)*8];
      acc[tn] = __builtin_amdgcn_mfma_f32_16x16x32_bf16(a, bl, acc[tn], 0,0,0);
      acc[tn] = __builtin_amdgcn_mfma_f32_16x16x32_bf16(a, bh, acc[tn], 0,0,0);
    }
  }
  #pragma unroll
  for (int tn=0;tn<4;tn++){
    int col = tn*16 + (lane&15);
    float bb = bias1[col];
    #pragma unroll
    for (int j=0;j<4;j++){
      int row = w*16 + (lane>>4)*4 + j;
      Y[(base+row)*64 + col] = f2bf(acc[tn][j] + bb);
    }
  }
}

// ---------------------------------------------------------------- layer 2: MFMA + stats + RAW maxpool (proven R6)
__global__ __launch_bounds__(256) void k_mm2a(const u16* __restrict__ Y1,
                                              const u16* __restrict__ Wb2h, const u16* __restrict__ Wb2l,
                                              const float* __restrict__ bias2, const float* __restrict__ gf1,
                                              const float* __restrict__ btf1, const float* __restrict__ stats1,
                                              float* __restrict__ stats2, float* __restrict__ out1)
{
  __shared__ u16 Xs[64*64];       // 8KB swizzled bf16 (row stride 128B)
  __shared__ u16 WH[8192];        // 16KB [tn*2+k0][lane][e], tn 0..7
  __shared__ u16 WL[8192];        // 16KB
  __shared__ float Ys[64*128];    // 32KB raw y, swizzled (row stride 512B)
  __shared__ float sc[64], sh[64];
  __shared__ float sred[512];
  int tid=threadIdx.x;
  if (tid<64){
    float mu = stats1[tid*2]*INV_ROWS;
    float var= stats1[tid*2+1]*INV_ROWS - mu*mu;
    float rs = 1.0f/sqrtf(var+EPSF);
    float s  = rs*gf1[tid];
    sc[tid]=s; sh[tid]=btf1[tid]-mu*s;
  }
  {
    const uint4* s4=(const uint4*)Wb2h; uint4* d4=(uint4*)WH;
    const uint4* s5=(const uint4*)Wb2l; uint4* d5=(uint4*)WL;
    for (int i=tid;i<1024;i+=256){ d4[i]=s4[i]; d5[i]=s5[i]; }
  }
  int w=tid>>6, lane=tid&63;
  int pg=tid>>7, po=tid&127;      // pool assignment: group (0,1), channel
  float accSum=0.f, accSq=0.f;    // per-thread channel stats across tiles
  __syncthreads();
  for (int tile=blockIdx.x; tile<8192; tile+=gridDim.x){
    size_t base=(size_t)tile*64;
    for (int i=tid;i<512;i+=256){
      int rl=i>>3, c0=(i&7)*8;
      uint4 v=*(const uint4*)(Y1 + (base+rl)*64 + c0);
      u32 arr[4]={v.x,v.y,v.z,v.w};
      u32 pk[4];
      #pragma unroll
      for (int q=0;q<4;q++){
        int cc=c0+q*2;
        float lo=bf2f((u16)(arr[q]&0xFFFFu));
        float hi=bf2f((u16)(arr[q]>>16));
        lo=fmaxf(0.f, lo*sc[cc]+sh[cc]);
        hi=fmaxf(0.f, hi*sc[cc+1]+sh[cc+1]);
        pk[q] = (u32)f2bf(lo) | ((u32)f2bf(hi)<<16);
      }
      uint4 o4; o4.x=pk[0]; o4.y=pk[1]; o4.z=pk[2]; o4.w=pk[3];
      int byteoff = rl*128 + ((c0*2) ^ ((rl&7)<<4));
      *(uint4*)((char*)Xs + byteoff) = o4;
    }
    __syncthreads();
    f32x4 acc[8];
    #pragma unroll
    for (int tn=0;tn<8;tn++){ acc[tn][0]=0.f; acc[tn][1]=0.f; acc[tn][2]=0.f; acc[tn][3]=0.f; }
    int arow = w*16 + (lane&15);
    #pragma unroll
    for (int k0=0;k0<2;k0++){
      int aoff = arow*128 + ((k0*64 + (lane>>4)*16) ^ ((arow&7)<<4));
      bf16x8 a = *(const bf16x8*)((const char*)Xs + aoff);
      #pragma unroll
      for (int tn=0;tn<8;tn++){
        bf16x8 bl = *(const bf16x8*)&WL[((tn*2+k0)*64+lane)*8];
        bf16x8 bh = *(const bf16x8*)&WH[((tn*2+k0)*64+lane)*8];
        acc[tn] = __builtin_amdgcn_mfma_f32_16x16x32_bf16(a, bl, acc[tn], 0,0,0);
        acc[tn] = __builtin_amdgcn_mfma_f32_16x16x32_bf16(a, bh, acc[tn], 0,0,0);
      }
    }
    #pragma unroll
    for (int tn=0;tn<8;tn++){
      int col = tn*16 + (lane&15);
      float bb = bias2[col];
      #pragma unroll
      for (int j=0;j<4;j++){
        int row = w*16 + (lane>>4)*4 + j;
        int byteoff = row*512 + ((col*4) ^ ((row&7)<<4));
        *(float*)((char*)Ys + byteoff) = acc[tn][j] + bb;
      }
    }
    __syncthreads();
    {
      float mx=-3e38f;
      #pragma unroll 4
      for (int k=0;k<32;k++){
        int row = pg*32 + k;
        int byteoff = row*512 + ((po*4) ^ ((row&7)<<4));
        float y = *(const float*)((const char*)Ys + byteoff);
        accSum += y; accSq += y*y;
        mx = fmaxf(mx, y);
      }
      int bm = tile*2 + pg; int bi = bm>>11, m = bm&2047;
      out1[((size_t)bi*128+po)*M_ + m] = mx;
    }
    __syncthreads();   // protect Xs/Ys for next tile
  }
  sred[tid]      = accSum;
  sred[256+tid]  = accSq;
  __syncthreads();
  if (tid<128){
    float s = sred[tid] + sred[tid+128];
    float q = sred[256+tid] + sred[256+tid+128];
    atomicAdd(&stats2[tid*2],   s);
    atomicAdd(&stats2[tid*2+1], q);
  }
}

// ---------------------------------------------------------------- final pool: in-place BN2+ReLU on raw maxes
__global__ __launch_bounds__(256) void k_pool(float* __restrict__ out1, const float* __restrict__ stats2,
                                              const float* __restrict__ gf2, const float* __restrict__ btf2)
{
  int idx = blockIdx.x*256 + threadIdx.x;     // 8*128*2048 = 2097152 elements
  int o = (idx >> 11) & 127;
  float mu = stats2[o*2]*INV_ROWS;
  float var= stats2[o*2+1]*INV_ROWS - mu*mu;
  float rs = 1.0f/sqrtf(var+EPSF);
  float s  = rs*gf2[o];
  float sh = btf2[o]-mu*s;
  out1[idx] = fmaxf(0.f, out1[idx]*s + sh);
}

// ---------------------------------------------------------------- launch
extern "C" void kernel_launch(void* const* d_in, const int* in_sizes, int n_in,
                              void* d_out, int out_size, void* d_ws, size_t ws_size,
                              hipStream_t stream)
{
  (void)in_sizes; (void)n_in; (void)out_size; (void)ws_size;
  const float* xyz =(const float*)d_in[0];
  const float* feat=(const float*)d_in[1];
  const float* w0=(const float*)d_in[2],  *b0=(const float*)d_in[3],  *g0=(const float*)d_in[4],  *bt0=(const float*)d_in[5];
  const float* w1=(const float*)d_in[6],  *b1=(const float*)d_in[7],  *g1=(const float*)d_in[8],  *bt1=(const float*)d_in[9];
  const float* w2=(const float*)d_in[10], *b2=(const float*)d_in[11], *g2=(const float*)d_in[12], *bt2=(const float*)d_in[13];
  float* out0=(float*)d_out;
  float* out1=out0 + (size_t)B_*M_*3;

  char* ws=(char*)d_ws;
  float* nxyz =(float*)(ws);              // 196608 B used
  u16*   Wb1h =(u16*)  (ws + 196608);     // 8192 B
  u16*   Wb1l =(u16*)  (ws + 204800);     // 8192 B
  u16*   Wb2h =(u16*)  (ws + 212992);     // 16384 B
  u16*   Wb2l =(u16*)  (ws + 229376);     // 16384 B (ends 245760 < 262144)
  int*   knn  =(int*)  (ws + 262144);     // 2097152
  u16*   Wb0h =(u16*)  (ws + 2359296);    // 12288 B (reuses dead Wt0 slot)
  u16*   Wb0l =(u16*)  (ws + 2376704);    // 12288 B (reuses dead Wt1 slot)
  float* biasf=(float*)(ws + 2425856);    // 1536
  float* gfp  =(float*)(ws + 2427392);    // 1536
  float* btfp =(float*)(ws + 2428928);    // 1536
  float* stats=(float*)(ws + 2430464);    // 3072
  u16*   featT=(u16*)  (ws + 2433536);    // 8388608
  u16*   Y0   =(u16*)  (ws + 10822144);   // 67108864  (total ~78 MB)

  k_prep<<<1,256,0,stream>>>(w0,b0,g0,bt0,w1,b1,g1,bt1,w2,b2,g2,bt2,biasf,gfp,btfp,stats,
                             Wb0h,Wb0l,Wb1h,Wb1l,Wb2h,Wb2l);
  k_tr<<<dim3(128,8),256,0,stream>>>(feat, featT);
  k_fps<<<B_,512,0,stream>>>(xyz, nxyz, out0);
  k_bq<<<2048,512,0,stream>>>(xyz, nxyz, knn);
  k_mm0<<<8192,256,0,stream>>>(xyz, featT, knn, nxyz, Wb0h, Wb0l, biasf+0, Y0);
  k_stats<64><<<128,256,0,stream>>>(Y0, stats+0);
  k_mm1<<<8192,256,0,stream>>>(Y0, Wb1h, Wb1l, biasf+128, gfp+0, btfp+0, stats+0);
  k_stats<64><<<128,256,0,stream>>>(Y0, stats+256);
  k_mm2a<<<512,256,0,stream>>>(Y0, Wb2h, Wb2l, biasf+256, gfp+128, btfp+128, stats+256, stats+512, out1);
  k_pool<<<8192,256,0,stream>>>(out1, stats+512, gfp+256, btfp+256);
}

// Round 11
// 2323.296 us; speedup vs baseline: 1.0819x; 1.0819x over previous
//
#include <hip/hip_runtime.h>
#include <hip/hip_bf16.h>
#include <stdint.h>

typedef unsigned short u16;
typedef unsigned int   u32;
typedef unsigned long long u64;
typedef float v2f __attribute__((ext_vector_type(2)));
typedef __attribute__((ext_vector_type(8))) short bf16x8;
typedef __attribute__((ext_vector_type(4))) float f32x4;

#define B_    8
#define N_    8192
#define M_    2048
#define NS_   32
#define CIN_  64
#define ROWS_ (B_*M_*NS_)          // 524288
#define BIGF  1e10f
#define EPSF  1e-5f
#define INV_ROWS (1.0f/524288.0f)  // 2^-19, exact

__device__ __forceinline__ u16 f2bf(float f){
  u32 x=__float_as_uint(f);
  return (u16)((x + 0x7FFFu + ((x>>16)&1u))>>16);   // RNE
}
__device__ __forceinline__ float bf2f(u16 u){ return __uint_as_float(((u32)u)<<16); }

// DPP full-wave max of non-negative u64 keys; result lands in lane 63.
__device__ __forceinline__ u64 wave_max_key(u64 k){
#define DPP_LVL(CTRL) { \
    u32 lo_=(u32)__builtin_amdgcn_update_dpp(0,(int)(u32)k,(CTRL),0xF,0xF,true); \
    u32 hi_=(u32)__builtin_amdgcn_update_dpp(0,(int)(u32)(k>>32),(CTRL),0xF,0xF,true); \
    u64 o_=((u64)hi_<<32)|(u64)lo_; \
    k=(o_>k)?o_:k; }
  DPP_LVL(0x111)  // row_shr:1
  DPP_LVL(0x112)  // row_shr:2
  DPP_LVL(0x114)  // row_shr:4
  DPP_LVL(0x118)  // row_shr:8
  DPP_LVL(0x142)  // row_bcast:15
  DPP_LVL(0x143)  // row_bcast:31  -> lane 63 holds wave max
#undef DPP_LVL
  return k;
}

// ---------------------------------------------------------------- prep (fp32 weights in)
// B-frag layout (16x16x32): col = tn*16 + (lane&15), k = k0*32 + ((lane>>4)&3)*8 + e.
// Split precision: w = bf16(hi) + bf16(w - hi)  (~2^-17 rel error).
// W0 fragments use the STAGED channel order: k<64 -> feat ch (w0 col 3+k),
// 64<=k<67 -> xyz ch (w0 col k-64), k>=67 -> 0. (3 K-steps, padded to 96.)
__global__ __launch_bounds__(256) void k_prep(
    const float* w0,const float* b0,const float* g0,const float* bt0,
    const float* w1,const float* b1,const float* g1,const float* bt1,
    const float* w2,const float* b2,const float* g2,const float* bt2,
    float* biasf,float* gf,float* btf,float* stats,
    u16* Wb0h, u16* Wb0l, u16* Wb1h, u16* Wb1l, u16* Wb2h, u16* Wb2l)
{
  int tid=threadIdx.x;
  for (int i=tid;i<768;i+=256) stats[i]=0.f;
  // W0 B-fragments (64 out cols -> tn 0..3, 3 k-steps)
  for (int i=tid;i<6144;i+=256){
    int e=i&7, lane=(i>>3)&63, idx=i>>9;        // idx = tn*3 + k0
    int tn=idx/3, k0=idx%3;
    int col = tn*16 + (lane&15);
    int k   = k0*32 + ((lane>>4)&3)*8 + e;      // 0..95
    float v = 0.f;
    if (k < 64)            v = w0[col*67 + 3 + k];
    else if (k < 67)       v = w0[col*67 + (k-64)];
    u16 hib = f2bf(v);
    Wb0h[i] = hib;
    Wb0l[i] = f2bf(v - bf2f(hib));
  }
  // W1 B-fragments (64 cols -> tn 0..3)
  for (int i=tid;i<4096;i+=256){
    int e=i&7, lane=(i>>3)&63, k0=(i>>9)&1, tn=i>>10;
    int col = tn*16 + (lane&15);
    int k   = k0*32 + ((lane>>4)&3)*8 + e;
    float v = w1[col*64 + k];
    u16 hib = f2bf(v);
    Wb1h[i] = hib;
    Wb1l[i] = f2bf(v - bf2f(hib));
  }
  // W2 B-fragments (128 cols -> tn 0..7)
  for (int i=tid;i<8192;i+=256){
    int e=i&7, lane=(i>>3)&63, k0=(i>>9)&1, tn=i>>10;
    int col = tn*16 + (lane&15);
    int k   = k0*32 + ((lane>>4)&3)*8 + e;
    float v = w2[col*64 + k];
    u16 hib = f2bf(v);
    Wb2h[i] = hib;
    Wb2l[i] = f2bf(v - bf2f(hib));
  }
  if (tid<64){
    biasf[0*128+tid]=b0[tid]; gf[0*128+tid]=g0[tid]; btf[0*128+tid]=bt0[tid];
    biasf[1*128+tid]=b1[tid]; gf[1*128+tid]=g1[tid]; btf[1*128+tid]=bt1[tid];
  }
  if (tid<128){
    biasf[2*128+tid]=b2[tid]; gf[2*128+tid]=g2[tid]; btf[2*128+tid]=bt2[tid];
  }
}

// ---------------------------------------------------------------- FPS + transpose (fused, heterogeneous grid)
// Blocks 0..7: the R1/R7 measured-best FPS body, VERBATIM (1733us floor: plain
// v2f distances with contract off, in-loop u64 keys, single u64 DPP ladder,
// parity skey publish + 8-load tree). All asm/prune variants (R2/R4/R9/R10)
// measured slower -- the compiler's own schedule wins; this is frozen.
// Blocks 8..1031: the feature transpose (independent work: feats->featT), rides
// on the 248 idle CUs during the 1733us fps tail. Tile overlays the fps sx LDS
// region (16.6KB < 32KB) -> no extra LDS, no occupancy change.
__global__ __launch_bounds__(512) void k_fpstr(const float* __restrict__ xyz,
                                               float* __restrict__ nxyz, float* __restrict__ out0,
                                               const float* __restrict__ feats, u16* __restrict__ featT)
{
#pragma clang fp contract(off)
  __shared__ float sx[N_], sy[N_], sz[N_];
  __shared__ int sidx[M_];
  __shared__ u64 skey[2][8];
  int tid=threadIdx.x;
  if (blockIdx.x >= 8){
    // ---------------- transpose part (512 threads; q covers 8 channels of 8)
    float (*t)[65] = (float(*)[65])sx;          // 64*65*4 = 16640B overlay on sx
    int idx = blockIdx.x - 8;                   // 0..1023
    int bb = idx >> 7, n0 = (idx & 127) * 64;
    int a=tid&63, q=tid>>6;                     // q in 0..7
    const float* fp = feats + (size_t)bb*CIN_*N_;
    #pragma unroll
    for (int s=0;s<8;s++){ int c=q*8+s; t[c][a]=fp[(size_t)c*N_ + n0 + a]; }
    __syncthreads();
    u16* op = featT + (size_t)bb*N_*CIN_;
    #pragma unroll
    for (int s=0;s<8;s++){ int n=q*8+s; op[(size_t)(n0+n)*CIN_ + a] = f2bf(t[a][n]); }
    return;
  }
  // ---------------- FPS part (R7 verbatim)
  int b=blockIdx.x;
  const float* xp = xyz + (size_t)b*N_*3;
  for (int i=tid;i<N_;i+=512){ sx[i]=xp[i*3]; sy[i]=xp[i*3+1]; sz[i]=xp[i*3+2]; }
  __syncthreads();
  v2f px[8],py[8],pz[8],md[8];
  int base = tid*16;
  #pragma unroll
  for (int p=0;p<8;p++){
    px[p]=*(const v2f*)&sx[base+2*p];
    py[p]=*(const v2f*)&sy[base+2*p];
    pz[p]=*(const v2f*)&sz[base+2*p];
    v2f m0; m0[0]=BIGF; m0[1]=BIGF; md[p]=m0;
  }
  u32 invb = 0xFFFFFFFFu - (u32)base;
  int far=0;
  int lane=tid&63, wv=tid>>6;
  for (int step=0; step<M_; step++){
    if (tid==0) sidx[step]=far;          // PRE-update emission
    float cxs=sx[far], cys=sy[far], czs=sz[far];
    v2f cx; cx[0]=cxs; cx[1]=cxs;
    v2f cy; cy[0]=cys; cy[1]=cys;
    v2f cz; cz[0]=czs; cz[1]=czs;
    u64 kb=0;
    #pragma unroll
    for (int p=0;p<8;p++){
      v2f dx=px[p]-cx, dy=py[p]-cy, dz=pz[p]-cz;
      v2f d=(dx*dx+dy*dy)+dz*dz;         // contract off: same assoc as ((xx+yy)+zz)
      v2f m=__builtin_elementwise_min(md[p],d);
      md[p]=m;
      u64 k0=((u64)__float_as_uint(m[0])<<32)|(u64)(invb-(u32)(2*p));
      u64 k1=((u64)__float_as_uint(m[1])<<32)|(u64)(invb-(u32)(2*p+1));
      u64 kp=(k1>k0)?k1:k0;              // equal dist -> k0 (lower idx) wins: larger ~idx
      kb=(kp>kb)?kp:kb;
    }
    kb = wave_max_key(kb);
    int par = step & 1;
    if (lane==63) skey[par][wv]=kb;
    __syncthreads();                     // single barrier per step
    u64 a0=skey[par][0],a1=skey[par][1],a2=skey[par][2],a3=skey[par][3];
    u64 a4=skey[par][4],a5=skey[par][5],a6=skey[par][6],a7=skey[par][7];
    a0=(a1>a0)?a1:a0; a2=(a3>a2)?a3:a2; a4=(a5>a4)?a5:a4; a6=(a7>a6)?a7:a6;
    a0=(a2>a0)?a2:a0; a4=(a6>a4)?a6:a4;
    a0=(a4>a0)?a4:a0;
    far = (int)(0xFFFFFFFFu - (u32)(a0 & 0xFFFFFFFFull));
  }
  // f32 output: exact raw coordinates of selected points
  for (int i=tid;i<M_;i+=512){
    int id = sidx[i];
    float x=sx[id], y=sy[id], z=sz[id];
    size_t o=(size_t)(b*M_+i)*3;
    nxyz[o]=x; nxyz[o+1]=y; nxyz[o+2]=z;
    out0[o]=x; out0[o+1]=y; out0[o+2]=z;
  }
}

// ---------------------------------------------------------------- ball query
#define BQCAP 512
__global__ __launch_bounds__(512) void k_bq(const float* __restrict__ xyz, const float* __restrict__ nxyz,
                                            int* __restrict__ knn)
{
  __shared__ float4 sP[N_];
  __shared__ float candd[8][BQCAP];
  __shared__ u16  candi[8][BQCAP];
  int tid=threadIdx.x;
  int cid0 = blockIdx.x*8;
  int b = cid0 >> 11;
  const float* xp = xyz + (size_t)b*N_*3;
  for (int i=tid;i<N_;i+=512){
    float x=xp[i*3], y=xp[i*3+1], z=xp[i*3+2];
    float x2 = __fmul_rn(x,x);
    x2 = __fadd_rn(x2, __fmul_rn(y,y));
    x2 = __fadd_rn(x2, __fmul_rn(z,z));
    sP[i]=make_float4(x,y,z,x2);
  }
  __syncthreads();
  int w=tid>>6, lane=tid&63;
  int cid = cid0 + w;
  float cx=nxyz[(size_t)cid*3], cy=nxyz[(size_t)cid*3+1], cz=nxyz[(size_t)cid*3+2];
  float c2 = __fmul_rn(cx,cx);
  c2 = __fadd_rn(c2, __fmul_rn(cy,cy));
  c2 = __fadd_rn(c2, __fmul_rn(cz,cz));
  int cnt=0;
  for (int i0=0;i0<N_;i0+=64){
    int i=i0+lane;
    float4 p=sP[i];
    float dot = __fmul_rn(cx,p.x);
    dot = __fadd_rn(dot, __fmul_rn(cy,p.y));
    dot = __fadd_rn(dot, __fmul_rn(cz,p.z));
    float d2 = __fsub_rn(__fadd_rn(c2,p.w), __fmul_rn(2.0f,dot));
    float d = sqrtf(fmaxf(d2,0.f));
    bool in = (d <= 0.4f);
    u64 msk = __ballot(in);
    int pos = cnt + __popcll(msk & ((1ull<<lane)-1ull));
    if (in && pos<BQCAP){ candd[w][pos]=d; candi[w][pos]=(u16)i; }
    cnt += __popcll(msk);
  }
  int R = cnt<BQCAP ? cnt : BQCAP;
  int* kout = knn + (size_t)cid*NS_;
  if (R >= NS_){
    for (int s=0;s<NS_;s++){
      u64 kb = ~0ull;                    // min identity
      for (int j=lane;j<R;j+=64){
        float v=candd[w][j];
        u64 k = ((u64)__float_as_uint(v)<<32) | (u64)(u32)j;
        kb = (k<kb)?k:kb;
      }
      u64 inv = wave_max_key(~kb);       // min via complemented max
      if (lane==63){
        u64 kw = ~inv;
        int bpp = (int)(u32)(kw & 0xFFFFFFFFull);
        kout[s]=candi[w][bpp];
        candd[w][bpp]=3e38f;             // same-wave DS in-order: visible next pass
      }
    }
  } else {
    if (lane<R) kout[lane]=candi[w][lane];
    int need = NS_-R, slot = R;
    for (int i0=0; i0<N_ && need>0; i0+=64){
      int i=i0+lane;
      float4 p=sP[i];
      float dot = __fmul_rn(cx,p.x);
      dot = __fadd_rn(dot, __fmul_rn(cy,p.y));
      dot = __fadd_rn(dot, __fmul_rn(cz,p.z));
      float d2 = __fsub_rn(__fadd_rn(c2,p.w), __fmul_rn(2.0f,dot));
      float d = sqrtf(fmaxf(d2,0.f));
      bool in = (d <= 0.4f);
      u64 mm = __ballot(!in);
      while (mm && need>0){
        int bpos = __ffsll((long long)mm)-1;
        if (lane==0) kout[slot] = i0+bpos;
        slot++; need--;
        mm &= mm-1;
      }
    }
  }
}

// ---------------------------------------------------------------- layer 0: MFMA (gather+concat fused)
__global__ __launch_bounds__(256) void k_mm0(const float* __restrict__ xyz, const u16* __restrict__ featT,
                                             const int* __restrict__ knn, const float* __restrict__ nxyz,
                                             const u16* __restrict__ Wb0h, const u16* __restrict__ Wb0l,
                                             const float* __restrict__ bias0, u16* __restrict__ Y0)
{
  __shared__ u16 Xs[64*128];     // 16KB, row stride 256B, swizzled
  __shared__ u16 WH[12*64*8];    // 12KB [tn*3+k0][lane][e]
  __shared__ u16 WL[12*64*8];    // 12KB
  int tid=threadIdx.x;
  {
    const uint4* s4=(const uint4*)Wb0h; uint4* d4=(uint4*)WH;
    const uint4* s5=(const uint4*)Wb0l; uint4* d5=(uint4*)WL;
    for (int i=tid;i<768;i+=256){ d4[i]=s4[i]; d5[i]=s5[i]; }
  }
  size_t base=(size_t)blockIdx.x*64;
  {
    int rl=tid>>2, t=tid&3;                 // 4 threads per row
    int row=(int)base+rl;
    int bm = row>>5, b = row>>16;
    int n  = knn[row];
    const uint4* fp = (const uint4*)(featT + ((size_t)b*N_ + n)*CIN_);
    char* xr = (char*)Xs + rl*256;
    u32 swz = (u32)((rl&7)<<4);
    uint4 v0=fp[t*2], v1=fp[t*2+1];
    *(uint4*)(xr + ((t*32)    ^ swz)) = v0;
    *(uint4*)(xr + ((t*32+16) ^ swz)) = v1;
    uint4 pz = make_uint4(0u,0u,0u,0u);
    if (t==0){
      const float* cp = nxyz + (size_t)bm*3;
      const float* xp = xyz + ((size_t)b*N_ + n)*3;
      u32 w01 = (u32)f2bf(xp[0]-cp[0]) | ((u32)f2bf(xp[1]-cp[1])<<16);
      u32 w2  = (u32)f2bf(xp[2]-cp[2]);
      pz.x = w01; pz.y = w2;
    }
    *(uint4*)(xr + ((128+t*16) ^ swz)) = pz;
  }
  __syncthreads();
  int w=tid>>6, lane=tid&63;
  f32x4 acc[4];
  #pragma unroll
  for (int tn=0;tn<4;tn++){ acc[tn][0]=0.f; acc[tn][1]=0.f; acc[tn][2]=0.f; acc[tn][3]=0.f; }
  int arow = w*16 + (lane&15);
  u32 aswz = (u32)((arow&7)<<4);
  #pragma unroll
  for (int k0=0;k0<3;k0++){
    int aoff = arow*256 + (int)(((u32)((k0*32 + ((lane>>4)&3)*8)*2)) ^ aswz);
    bf16x8 a = *(const bf16x8*)((const char*)Xs + aoff);
    #pragma unroll
    for (int tn=0;tn<4;tn++){
      bf16x8 bl = *(const bf16x8*)&WL[((tn*3+k0)*64+lane)*8];
      bf16x8 bh = *(const bf16x8*)&WH[((tn*3+k0)*64+lane)*8];
      acc[tn] = __builtin_amdgcn_mfma_f32_16x16x32_bf16(a, bl, acc[tn], 0,0,0);
      acc[tn] = __builtin_amdgcn_mfma_f32_16x16x32_bf16(a, bh, acc[tn], 0,0,0);
    }
  }
  #pragma unroll
  for (int tn=0;tn<4;tn++){
    int col = tn*16 + (lane&15);
    float bb = bias0[col];
    #pragma unroll
    for (int j=0;j<4;j++){
      int row = w*16 + (lane>>4)*4 + j;
      Y0[(base+row)*64 + col] = f2bf(acc[tn][j] + bb);
    }
  }
}

// ---------------------------------------------------------------- channel stats (sum, sumsq)
template<int C>
__global__ __launch_bounds__(256) void k_stats(const u16* __restrict__ Y, float* __restrict__ statsOut)
{
  __shared__ float sred[4][128];
  int tid=threadIdx.x;
  int c0=(tid&7)*8;          // 8 channels per thread
  int rg=tid>>3;             // 32 row-groups per block
  float s[8], ss[8];
  #pragma unroll
  for (int k=0;k<8;k++){ s[k]=0.f; ss[k]=0.f; }
  for (size_t r=(size_t)blockIdx.x*32+rg; r<ROWS_; r+=(size_t)gridDim.x*32){
    uint4 v=*(const uint4*)&Y[r*64+c0];
    u32 a[4]={v.x,v.y,v.z,v.w};
    #pragma unroll
    for (int q=0;q<4;q++){
      float lo=bf2f((u16)(a[q]&0xFFFFu));
      float hi=bf2f((u16)(a[q]>>16));
      s[q*2]+=lo;   ss[q*2]+=lo*lo;
      s[q*2+1]+=hi; ss[q*2+1]+=hi*hi;
    }
  }
  #pragma unroll
  for (int off=32; off>=8; off>>=1){
    #pragma unroll
    for (int k=0;k<8;k++){
      s[k]+=__shfl_down(s[k],off);
      ss[k]+=__shfl_down(ss[k],off);
    }
  }
  int lane=tid&63, wv=tid>>6;
  if (lane<8){
    #pragma unroll
    for (int k=0;k<8;k++){
      int ch=lane*8+k;
      sred[wv][ch]=s[k];
      sred[wv][64+ch]=ss[k];
    }
  }
  __syncthreads();
  if (tid<128){
    float a=sred[0][tid]+sred[1][tid]+sred[2][tid]+sred[3][tid];
    int ch=tid&63, which=tid>>6;
    atomicAdd(&statsOut[ch*2+which], a);
  }
}

// ---------------------------------------------------------------- layer 1: MFMA (proven R5)
__global__ __launch_bounds__(256) void k_mm1(u16* __restrict__ Y,
                                             const u16* __restrict__ Wb1h, const u16* __restrict__ Wb1l,
                                             const float* __restrict__ bias1, const float* __restrict__ gf0,
                                             const float* __restrict__ btf0, const float* __restrict__ stats0)
{
  __shared__ u16 Xs[64*64];      // 8KB, swizzled
  __shared__ u16 WH[8*64*8];     // 8KB  [tn*2+k0][lane][e]
  __shared__ u16 WL[8*64*8];     // 8KB
  __shared__ float sc[64], sh[64];
  int tid=threadIdx.x;
  if (tid<64){
    float mu = stats0[tid*2]*INV_ROWS;
    float var= stats0[tid*2+1]*INV_ROWS - mu*mu;
    float rs = 1.0f/sqrtf(var+EPSF);
    float s  = rs*gf0[tid];
    sc[tid]=s; sh[tid]=btf0[tid]-mu*s;
  }
  {
    const uint4* sh4=(const uint4*)Wb1h; uint4* dh4=(uint4*)WH;
    const uint4* sl4=(const uint4*)Wb1l; uint4* dl4=(uint4*)WL;
    dh4[tid]=sh4[tid]; dh4[tid+256]=sh4[tid+256];
    dl4[tid]=sl4[tid]; dl4[tid+256]=sl4[tid+256];
  }
  __syncthreads();
  size_t base=(size_t)blockIdx.x*64;
  for (int i=tid;i<512;i+=256){
    int rl=i>>3, c0=(i&7)*8;
    uint4 v=*(const uint4*)(Y + (base+rl)*64 + c0);
    u32 arr[4]={v.x,v.y,v.z,v.w};
    u32 pk[4];
    #pragma unroll
    for (int q=0;q<4;q++){
      int cc=c0+q*2;
      float lo=bf2f((u16)(arr[q]&0xFFFFu));
      float hi=bf2f((u16)(arr[q]>>16));
      lo=fmaxf(0.f, lo*sc[cc]+sh[cc]);
      hi=fmaxf(0.f, hi*sc[cc+1]+sh[cc+1]);
      pk[q] = (u32)f2bf(lo) | ((u32)f2bf(hi)<<16);
    }
    uint4 o4; o4.x=pk[0]; o4.y=pk[1]; o4.z=pk[2]; o4.w=pk[3];
    int byteoff = rl*128 + ((c0*2) ^ ((rl&7)<<4));
    *(uint4*)((char*)Xs + byteoff) = o4;
  }
  __syncthreads();
  int w=tid>>6, lane=tid&63;
  f32x4 acc[4];
  #pragma unroll
  for (int tn=0;tn<4;tn++){ acc[tn][0]=0.f; acc[tn][1]=0.f; acc[tn][2]=0.f; acc[tn][3]=0.f; }
  int arow = w*16 + (lane&15);
  #pragma unroll
  for (int k0=0;k0<2;k0++){
    int aoff = arow*128 + ((k0*64 + (lane>>4)*16) ^ ((arow&7)<<4));
    bf16x8 a = *(const bf16x8*)((const char*)Xs + aoff);
    #pragma unroll
    for (int tn=0;tn<4;tn++){
      bf16x8 bl = *(const bf16x8*)&WL[((tn*2+k0)*64+lane)*8];
      bf16x8 bh = *(const bf16x8*)&WH[((tn*2+k0)*64+lane)*8];
      acc[tn] = __builtin_amdgcn_mfma_f32_16x16x32_bf16(a, bl, acc[tn], 0,0,0);
      acc[tn] = __builtin_amdgcn_mfma_f32_16x16x32_bf16(a, bh, acc[tn], 0,0,0);
    }
  }
  #pragma unroll
  for (int tn=0;tn<4;tn++){
    int col = tn*16 + (lane&15);
    float bb = bias1[col];
    #pragma unroll
    for (int j=0;j<4;j++){
      int row = w*16 + (lane>>4)*4 + j;
      Y[(base+row)*64 + col] = f2bf(acc[tn][j] + bb);
    }
  }
}

// ---------------------------------------------------------------- layer 2: MFMA + stats + RAW maxpool (proven R6)
__global__ __launch_bounds__(256) void k_mm2a(const u16* __restrict__ Y1,
                                              const u16* __restrict__ Wb2h, const u16* __restrict__ Wb2l,
                                              const float* __restrict__ bias2, const float* __restrict__ gf1,
                                              const float* __restrict__ btf1, const float* __restrict__ stats1,
                                              float* __restrict__ stats2, float* __restrict__ out1)
{
  __shared__ u16 Xs[64*64];       // 8KB swizzled bf16 (row stride 128B)
  __shared__ u16 WH[8192];        // 16KB [tn*2+k0][lane][e], tn 0..7
  __shared__ u16 WL[8192];        // 16KB
  __shared__ float Ys[64*128];    // 32KB raw y, swizzled (row stride 512B)
  __shared__ float sc[64], sh[64];
  __shared__ float sred[512];
  int tid=threadIdx.x;
  if (tid<64){
    float mu = stats1[tid*2]*INV_ROWS;
    float var= stats1[tid*2+1]*INV_ROWS - mu*mu;
    float rs = 1.0f/sqrtf(var+EPSF);
    float s  = rs*gf1[tid];
    sc[tid]=s; sh[tid]=btf1[tid]-mu*s;
  }
  {
    const uint4* s4=(const uint4*)Wb2h; uint4* d4=(uint4*)WH;
    const uint4* s5=(const uint4*)Wb2l; uint4* d5=(uint4*)WL;
    for (int i=tid;i<1024;i+=256){ d4[i]=s4[i]; d5[i]=s5[i]; }
  }
  int w=tid>>6, lane=tid&63;
  int pg=tid>>7, po=tid&127;      // pool assignment: group (0,1), channel
  float accSum=0.f, accSq=0.f;    // per-thread channel stats across tiles
  __syncthreads();
  for (int tile=blockIdx.x; tile<8192; tile+=gridDim.x){
    size_t base=(size_t)tile*64;
    for (int i=tid;i<512;i+=256){
      int rl=i>>3, c0=(i&7)*8;
      uint4 v=*(const uint4*)(Y1 + (base+rl)*64 + c0);
      u32 arr[4]={v.x,v.y,v.z,v.w};
      u32 pk[4];
      #pragma unroll
      for (int q=0;q<4;q++){
        int cc=c0+q*2;
        float lo=bf2f((u16)(arr[q]&0xFFFFu));
        float hi=bf2f((u16)(arr[q]>>16));
        lo=fmaxf(0.f, lo*sc[cc]+sh[cc]);
        hi=fmaxf(0.f, hi*sc[cc+1]+sh[cc+1]);
        pk[q] = (u32)f2bf(lo) | ((u32)f2bf(hi)<<16);
      }
      uint4 o4; o4.x=pk[0]; o4.y=pk[1]; o4.z=pk[2]; o4.w=pk[3];
      int byteoff = rl*128 + ((c0*2) ^ ((rl&7)<<4));
      *(uint4*)((char*)Xs + byteoff) = o4;
    }
    __syncthreads();
    f32x4 acc[8];
    #pragma unroll
    for (int tn=0;tn<8;tn++){ acc[tn][0]=0.f; acc[tn][1]=0.f; acc[tn][2]=0.f; acc[tn][3]=0.f; }
    int arow = w*16 + (lane&15);
    #pragma unroll
    for (int k0=0;k0<2;k0++){
      int aoff = arow*128 + ((k0*64 + (lane>>4)*16) ^ ((arow&7)<<4));
      bf16x8 a = *(const bf16x8*)((const char*)Xs + aoff);
      #pragma unroll
      for (int tn=0;tn<8;tn++){
        bf16x8 bl = *(const bf16x8*)&WL[((tn*2+k0)*64+lane)*8];
        bf16x8 bh = *(const bf16x8*)&WH[((tn*2+k0)*64+lane)*8];
        acc[tn] = __builtin_amdgcn_mfma_f32_16x16x32_bf16(a, bl, acc[tn], 0,0,0);
        acc[tn] = __builtin_amdgcn_mfma_f32_16x16x32_bf16(a, bh, acc[tn], 0,0,0);
      }
    }
    #pragma unroll
    for (int tn=0;tn<8;tn++){
      int col = tn*16 + (lane&15);
      float bb = bias2[col];
      #pragma unroll
      for (int j=0;j<4;j++){
        int row = w*16 + (lane>>4)*4 + j;
        int byteoff = row*512 + ((col*4) ^ ((row&7)<<4));
        *(float*)((char*)Ys + byteoff) = acc[tn][j] + bb;
      }
    }
    __syncthreads();
    {
      float mx=-3e38f;
      #pragma unroll 4
      for (int k=0;k<32;k++){
        int row = pg*32 + k;
        int byteoff = row*512 + ((po*4) ^ ((row&7)<<4));
        float y = *(const float*)((const char*)Ys + byteoff);
        accSum += y; accSq += y*y;
        mx = fmaxf(mx, y);
      }
      int bm = tile*2 + pg; int bi = bm>>11, m = bm&2047;
      out1[((size_t)bi*128+po)*M_ + m] = mx;
    }
    __syncthreads();   // protect Xs/Ys for next tile
  }
  sred[tid]      = accSum;
  sred[256+tid]  = accSq;
  __syncthreads();
  if (tid<128){
    float s = sred[tid] + sred[tid+128];
    float q = sred[256+tid] + sred[256+tid+128];
    atomicAdd(&stats2[tid*2],   s);
    atomicAdd(&stats2[tid*2+1], q);
  }
}

// ---------------------------------------------------------------- final pool: in-place BN2+ReLU on raw maxes
__global__ __launch_bounds__(256) void k_pool(float* __restrict__ out1, const float* __restrict__ stats2,
                                              const float* __restrict__ gf2, const float* __restrict__ btf2)
{
  int idx = blockIdx.x*256 + threadIdx.x;     // 8*128*2048 = 2097152 elements
  int o = (idx >> 11) & 127;
  float mu = stats2[o*2]*INV_ROWS;
  float var= stats2[o*2+1]*INV_ROWS - mu*mu;
  float rs = 1.0f/sqrtf(var+EPSF);
  float s  = rs*gf2[o];
  float sh = btf2[o]-mu*s;
  out1[idx] = fmaxf(0.f, out1[idx]*s + sh);
}

// ---------------------------------------------------------------- launch
extern "C" void kernel_launch(void* const* d_in, const int* in_sizes, int n_in,
                              void* d_out, int out_size, void* d_ws, size_t ws_size,
                              hipStream_t stream)
{
  (void)in_sizes; (void)n_in; (void)out_size; (void)ws_size;
  const float* xyz =(const float*)d_in[0];
  const float* feat=(const float*)d_in[1];
  const float* w0=(const float*)d_in[2],  *b0=(const float*)d_in[3],  *g0=(const float*)d_in[4],  *bt0=(const float*)d_in[5];
  const float* w1=(const float*)d_in[6],  *b1=(const float*)d_in[7],  *g1=(const float*)d_in[8],  *bt1=(const float*)d_in[9];
  const float* w2=(const float*)d_in[10], *b2=(const float*)d_in[11], *g2=(const float*)d_in[12], *bt2=(const float*)d_in[13];
  float* out0=(float*)d_out;
  float* out1=out0 + (size_t)B_*M_*3;

  char* ws=(char*)d_ws;
  float* nxyz =(float*)(ws);              // 196608 B used
  u16*   Wb1h =(u16*)  (ws + 196608);     // 8192 B
  u16*   Wb1l =(u16*)  (ws + 204800);     // 8192 B
  u16*   Wb2h =(u16*)  (ws + 212992);     // 16384 B
  u16*   Wb2l =(u16*)  (ws + 229376);     // 16384 B (ends 245760 < 262144)
  int*   knn  =(int*)  (ws + 262144);     // 2097152
  u16*   Wb0h =(u16*)  (ws + 2359296);    // 12288 B (reuses dead Wt0 slot)
  u16*   Wb0l =(u16*)  (ws + 2376704);    // 12288 B (reuses dead Wt1 slot)
  float* biasf=(float*)(ws + 2425856);    // 1536
  float* gfp  =(float*)(ws + 2427392);    // 1536
  float* btfp =(float*)(ws + 2428928);    // 1536
  float* stats=(float*)(ws + 2430464);    // 3072
  u16*   featT=(u16*)  (ws + 2433536);    // 8388608
  u16*   Y0   =(u16*)  (ws + 10822144);   // 67108864  (total ~78 MB)

  k_prep<<<1,256,0,stream>>>(w0,b0,g0,bt0,w1,b1,g1,bt1,w2,b2,g2,bt2,biasf,gfp,btfp,stats,
                             Wb0h,Wb0l,Wb1h,Wb1l,Wb2h,Wb2l);
  k_fpstr<<<8+1024,512,0,stream>>>(xyz, nxyz, out0, feat, featT);
  k_bq<<<2048,512,0,stream>>>(xyz, nxyz, knn);
  k_mm0<<<8192,256,0,stream>>>(xyz, featT, knn, nxyz, Wb0h, Wb0l, biasf+0, Y0);
  k_stats<64><<<128,256,0,stream>>>(Y0, stats+0);
  k_mm1<<<8192,256,0,stream>>>(Y0, Wb1h, Wb1l, biasf+128, gfp+0, btfp+0, stats+0);
  k_stats<64><<<128,256,0,stream>>>(Y0, stats+256);
  k_mm2a<<<512,256,0,stream>>>(Y0, Wb2h, Wb2l, biasf+256, gfp+128, btfp+128, stats+256, stats+512, out1);
  k_pool<<<8192,256,0,stream>>>(out1, stats+512, gfp+256, btfp+256);
}

// Round 12
// 2185.616 us; speedup vs baseline: 1.1500x; 1.0630x over previous
//
#include <hip/hip_runtime.h>
#include <hip/hip_bf16.h>
#include <stdint.h>

typedef unsigned short u16;
typedef unsigned int   u32;
typedef unsigned long long u64;
typedef float v2f __attribute__((ext_vector_type(2)));
typedef __attribute__((ext_vector_type(8))) short bf16x8;
typedef __attribute__((ext_vector_type(4))) float f32x4;

#define B_    8
#define N_    8192
#define M_    2048
#define NS_   32
#define CIN_  64
#define ROWS_ (B_*M_*NS_)          // 524288
#define BIGF  1e10f
#define EPSF  1e-5f
#define INV_ROWS (1.0f/524288.0f)  // 2^-19, exact

__device__ __forceinline__ u16 f2bf(float f){
  u32 x=__float_as_uint(f);
  return (u16)((x + 0x7FFFu + ((x>>16)&1u))>>16);   // RNE
}
__device__ __forceinline__ float bf2f(u16 u){ return __uint_as_float(((u32)u)<<16); }

// DPP full-wave max of non-negative u64 keys; result lands in lane 63.
__device__ __forceinline__ u64 wave_max_key(u64 k){
#define DPP_LVL(CTRL) { \
    u32 lo_=(u32)__builtin_amdgcn_update_dpp(0,(int)(u32)k,(CTRL),0xF,0xF,true); \
    u32 hi_=(u32)__builtin_amdgcn_update_dpp(0,(int)(u32)(k>>32),(CTRL),0xF,0xF,true); \
    u64 o_=((u64)hi_<<32)|(u64)lo_; \
    k=(o_>k)?o_:k; }
  DPP_LVL(0x111)  // row_shr:1
  DPP_LVL(0x112)  // row_shr:2
  DPP_LVL(0x114)  // row_shr:4
  DPP_LVL(0x118)  // row_shr:8
  DPP_LVL(0x142)  // row_bcast:15
  DPP_LVL(0x143)  // row_bcast:31  -> lane 63 holds wave max
#undef DPP_LVL
  return k;
}

// ---------------------------------------------------------------- prep (fp32 weights in)
// B-frag layout (16x16x32): col = tn*16 + (lane&15), k = k0*32 + ((lane>>4)&3)*8 + e.
// Split precision: w = bf16(hi) + bf16(w - hi)  (~2^-17 rel error).
// W0 fragments use the STAGED channel order: k<64 -> feat ch (w0 col 3+k),
// 64<=k<67 -> xyz ch (w0 col k-64), k>=67 -> 0. (3 K-steps, padded to 96.)
__global__ __launch_bounds__(256) void k_prep(
    const float* w0,const float* b0,const float* g0,const float* bt0,
    const float* w1,const float* b1,const float* g1,const float* bt1,
    const float* w2,const float* b2,const float* g2,const float* bt2,
    float* biasf,float* gf,float* btf,float* stats,
    u16* Wb0h, u16* Wb0l, u16* Wb1h, u16* Wb1l, u16* Wb2h, u16* Wb2l)
{
  int tid=threadIdx.x;
  for (int i=tid;i<768;i+=256) stats[i]=0.f;
  // W0 B-fragments (64 out cols -> tn 0..3, 3 k-steps)
  for (int i=tid;i<6144;i+=256){
    int e=i&7, lane=(i>>3)&63, idx=i>>9;        // idx = tn*3 + k0
    int tn=idx/3, k0=idx%3;
    int col = tn*16 + (lane&15);
    int k   = k0*32 + ((lane>>4)&3)*8 + e;      // 0..95
    float v = 0.f;
    if (k < 64)            v = w0[col*67 + 3 + k];
    else if (k < 67)       v = w0[col*67 + (k-64)];
    u16 hib = f2bf(v);
    Wb0h[i] = hib;
    Wb0l[i] = f2bf(v - bf2f(hib));
  }
  // W1 B-fragments (64 cols -> tn 0..3)
  for (int i=tid;i<4096;i+=256){
    int e=i&7, lane=(i>>3)&63, k0=(i>>9)&1, tn=i>>10;
    int col = tn*16 + (lane&15);
    int k   = k0*32 + ((lane>>4)&3)*8 + e;
    float v = w1[col*64 + k];
    u16 hib = f2bf(v);
    Wb1h[i] = hib;
    Wb1l[i] = f2bf(v - bf2f(hib));
  }
  // W2 B-fragments (128 cols -> tn 0..7)
  for (int i=tid;i<8192;i+=256){
    int e=i&7, lane=(i>>3)&63, k0=(i>>9)&1, tn=i>>10;
    int col = tn*16 + (lane&15);
    int k   = k0*32 + ((lane>>4)&3)*8 + e;
    float v = w2[col*64 + k];
    u16 hib = f2bf(v);
    Wb2h[i] = hib;
    Wb2l[i] = f2bf(v - bf2f(hib));
  }
  if (tid<64){
    biasf[0*128+tid]=b0[tid]; gf[0*128+tid]=g0[tid]; btf[0*128+tid]=bt0[tid];
    biasf[1*128+tid]=b1[tid]; gf[1*128+tid]=g1[tid]; btf[1*128+tid]=bt1[tid];
  }
  if (tid<128){
    biasf[2*128+tid]=b2[tid]; gf[2*128+tid]=g2[tid]; btf[2*128+tid]=bt2[tid];
  }
}

// ---------------------------------------------------------------- FPS + transpose (fused, heterogeneous grid)
// Blocks 0..7: R1/R7 measured-best FPS body, frozen (1740us floor).
// Blocks 8..1031: feature transpose riding the idle CUs.
__global__ __launch_bounds__(512) void k_fpstr(const float* __restrict__ xyz,
                                               float* __restrict__ nxyz, float* __restrict__ out0,
                                               const float* __restrict__ feats, u16* __restrict__ featT)
{
#pragma clang fp contract(off)
  __shared__ float sx[N_], sy[N_], sz[N_];
  __shared__ int sidx[M_];
  __shared__ u64 skey[2][8];
  int tid=threadIdx.x;
  if (blockIdx.x >= 8){
    // ---------------- transpose part (512 threads; q covers 8 channels of 8)
    float (*t)[65] = (float(*)[65])sx;          // 64*65*4 = 16640B overlay on sx
    int idx = blockIdx.x - 8;                   // 0..1023
    int bb = idx >> 7, n0 = (idx & 127) * 64;
    int a=tid&63, q=tid>>6;                     // q in 0..7
    const float* fp = feats + (size_t)bb*CIN_*N_;
    #pragma unroll
    for (int s=0;s<8;s++){ int c=q*8+s; t[c][a]=fp[(size_t)c*N_ + n0 + a]; }
    __syncthreads();
    u16* op = featT + (size_t)bb*N_*CIN_;
    #pragma unroll
    for (int s=0;s<8;s++){ int n=q*8+s; op[(size_t)(n0+n)*CIN_ + a] = f2bf(t[a][n]); }
    return;
  }
  // ---------------- FPS part (R7 verbatim)
  int b=blockIdx.x;
  const float* xp = xyz + (size_t)b*N_*3;
  for (int i=tid;i<N_;i+=512){ sx[i]=xp[i*3]; sy[i]=xp[i*3+1]; sz[i]=xp[i*3+2]; }
  __syncthreads();
  v2f px[8],py[8],pz[8],md[8];
  int base = tid*16;
  #pragma unroll
  for (int p=0;p<8;p++){
    px[p]=*(const v2f*)&sx[base+2*p];
    py[p]=*(const v2f*)&sy[base+2*p];
    pz[p]=*(const v2f*)&sz[base+2*p];
    v2f m0; m0[0]=BIGF; m0[1]=BIGF; md[p]=m0;
  }
  u32 invb = 0xFFFFFFFFu - (u32)base;
  int far=0;
  int lane=tid&63, wv=tid>>6;
  for (int step=0; step<M_; step++){
    if (tid==0) sidx[step]=far;          // PRE-update emission
    float cxs=sx[far], cys=sy[far], czs=sz[far];
    v2f cx; cx[0]=cxs; cx[1]=cxs;
    v2f cy; cy[0]=cys; cy[1]=cys;
    v2f cz; cz[0]=czs; cz[1]=czs;
    u64 kb=0;
    #pragma unroll
    for (int p=0;p<8;p++){
      v2f dx=px[p]-cx, dy=py[p]-cy, dz=pz[p]-cz;
      v2f d=(dx*dx+dy*dy)+dz*dz;         // contract off: same assoc as ((xx+yy)+zz)
      v2f m=__builtin_elementwise_min(md[p],d);
      md[p]=m;
      u64 k0=((u64)__float_as_uint(m[0])<<32)|(u64)(invb-(u32)(2*p));
      u64 k1=((u64)__float_as_uint(m[1])<<32)|(u64)(invb-(u32)(2*p+1));
      u64 kp=(k1>k0)?k1:k0;              // equal dist -> k0 (lower idx) wins: larger ~idx
      kb=(kp>kb)?kp:kb;
    }
    kb = wave_max_key(kb);
    int par = step & 1;
    if (lane==63) skey[par][wv]=kb;
    __syncthreads();                     // single barrier per step
    u64 a0=skey[par][0],a1=skey[par][1],a2=skey[par][2],a3=skey[par][3];
    u64 a4=skey[par][4],a5=skey[par][5],a6=skey[par][6],a7=skey[par][7];
    a0=(a1>a0)?a1:a0; a2=(a3>a2)?a3:a2; a4=(a5>a4)?a5:a4; a6=(a7>a6)?a7:a6;
    a0=(a2>a0)?a2:a0; a4=(a6>a4)?a6:a4;
    a0=(a4>a0)?a4:a0;
    far = (int)(0xFFFFFFFFu - (u32)(a0 & 0xFFFFFFFFull));
  }
  // f32 output: exact raw coordinates of selected points
  for (int i=tid;i<M_;i+=512){
    int id = sidx[i];
    float x=sx[id], y=sy[id], z=sz[id];
    size_t o=(size_t)(b*M_+i)*3;
    nxyz[o]=x; nxyz[o+1]=y; nxyz[o+2]=z;
    out0[o]=x; out0[o+1]=y; out0[o+2]=z;
  }
}

// ---------------------------------------------------------------- ball query
// R12: sP LDS staging DROPPED -- xyz is 96KB/batch, fully L2-resident; staging
// was pure overhead and capped occupancy at 1 block/CU (152KB LDS). Scans read
// global directly with the IDENTICAL op order (x2 recomputed with same ops;
// same d2/d/in/ballot) -> same candidates, same selections, bit-exact. LDS now
// 24KB (candd/candi only) -> 4+ blocks/CU; no __syncthreads (waves independent).
#define BQCAP 512
__global__ __launch_bounds__(512) void k_bq(const float* __restrict__ xyz, const float* __restrict__ nxyz,
                                            int* __restrict__ knn)
{
  __shared__ float candd[8][BQCAP];
  __shared__ u16  candi[8][BQCAP];
  int tid=threadIdx.x;
  int cid0 = blockIdx.x*8;
  int b = cid0 >> 11;
  const float* xp = xyz + (size_t)b*N_*3;
  int w=tid>>6, lane=tid&63;
  int cid = cid0 + w;
  float cx=nxyz[(size_t)cid*3], cy=nxyz[(size_t)cid*3+1], cz=nxyz[(size_t)cid*3+2];
  float c2 = __fmul_rn(cx,cx);
  c2 = __fadd_rn(c2, __fmul_rn(cy,cy));
  c2 = __fadd_rn(c2, __fmul_rn(cz,cz));
  int cnt=0;
  for (int i0=0;i0<N_;i0+=64){
    int i=i0+lane;
    float x=xp[i*3], y=xp[i*3+1], z=xp[i*3+2];
    float pw = __fmul_rn(x,x);
    pw = __fadd_rn(pw, __fmul_rn(y,y));
    pw = __fadd_rn(pw, __fmul_rn(z,z));
    float dot = __fmul_rn(cx,x);
    dot = __fadd_rn(dot, __fmul_rn(cy,y));
    dot = __fadd_rn(dot, __fmul_rn(cz,z));
    float d2 = __fsub_rn(__fadd_rn(c2,pw), __fmul_rn(2.0f,dot));
    float d = sqrtf(fmaxf(d2,0.f));
    bool in = (d <= 0.4f);
    u64 msk = __ballot(in);
    int pos = cnt + __popcll(msk & ((1ull<<lane)-1ull));
    if (in && pos<BQCAP){ candd[w][pos]=d; candi[w][pos]=(u16)i; }
    cnt += __popcll(msk);
  }
  int R = cnt<BQCAP ? cnt : BQCAP;
  int* kout = knn + (size_t)cid*NS_;
  if (R >= NS_){
    for (int s=0;s<NS_;s++){
      u64 kb = ~0ull;                    // min identity
      for (int j=lane;j<R;j+=64){
        float v=candd[w][j];
        u64 k = ((u64)__float_as_uint(v)<<32) | (u64)(u32)j;
        kb = (k<kb)?k:kb;
      }
      u64 inv = wave_max_key(~kb);       // min via complemented max
      if (lane==63){
        u64 kw = ~inv;
        int bpp = (int)(u32)(kw & 0xFFFFFFFFull);
        kout[s]=candi[w][bpp];
        candd[w][bpp]=3e38f;             // same-wave DS in-order: visible next pass
      }
    }
  } else {
    if (lane<R) kout[lane]=candi[w][lane];
    int need = NS_-R, slot = R;
    for (int i0=0; i0<N_ && need>0; i0+=64){
      int i=i0+lane;
      float x=xp[i*3], y=xp[i*3+1], z=xp[i*3+2];
      float pw = __fmul_rn(x,x);
      pw = __fadd_rn(pw, __fmul_rn(y,y));
      pw = __fadd_rn(pw, __fmul_rn(z,z));
      float dot = __fmul_rn(cx,x);
      dot = __fadd_rn(dot, __fmul_rn(cy,y));
      dot = __fadd_rn(dot, __fmul_rn(cz,z));
      float d2 = __fsub_rn(__fadd_rn(c2,pw), __fmul_rn(2.0f,dot));
      float d = sqrtf(fmaxf(d2,0.f));
      bool in = (d <= 0.4f);
      u64 mm = __ballot(!in);
      while (mm && need>0){
        int bpos = __ffsll((long long)mm)-1;
        if (lane==0) kout[slot] = i0+bpos;
        slot++; need--;
        mm &= mm-1;
      }
    }
  }
}

// ---------------------------------------------------------------- layer 0: MFMA (gather+concat fused)
// R12: 512-block grid-stride + fused channel stats (mm2a pattern): per-thread
// register sum/sumsq of the STORED bf16 values (bf2f(f2bf(v)) == what k_stats
// read), LDS-combine, 64 global atomics/block (512/address, proven density).
__global__ __launch_bounds__(256) void k_mm0(const float* __restrict__ xyz, const u16* __restrict__ featT,
                                             const int* __restrict__ knn, const float* __restrict__ nxyz,
                                             const u16* __restrict__ Wb0h, const u16* __restrict__ Wb0l,
                                             const float* __restrict__ bias0, u16* __restrict__ Y0,
                                             float* __restrict__ stats0)
{
  __shared__ u16 Xs[64*128];     // 16KB, row stride 256B, swizzled
  __shared__ u16 WH[12*64*8];    // 12KB [tn*3+k0][lane][e]
  __shared__ u16 WL[12*64*8];    // 12KB
  __shared__ float cs[128];
  int tid=threadIdx.x;
  {
    const uint4* s4=(const uint4*)Wb0h; uint4* d4=(uint4*)WH;
    const uint4* s5=(const uint4*)Wb0l; uint4* d5=(uint4*)WL;
    for (int i=tid;i<768;i+=256){ d4[i]=s4[i]; d5[i]=s5[i]; }
  }
  for (int i=tid;i<128;i+=256) cs[i]=0.f;
  int w=tid>>6, lane=tid&63;
  int rl=tid>>2, t=tid&3;                 // 4 threads per row (staging)
  float sSum[4]={0.f,0.f,0.f,0.f}, sSq[4]={0.f,0.f,0.f,0.f};
  __syncthreads();
  for (int tile=blockIdx.x; tile<8192; tile+=gridDim.x){
    size_t base=(size_t)tile*64;
    {
      int row=(int)base+rl;
      int bm = row>>5, b = row>>16;
      int n  = knn[row];
      const uint4* fp = (const uint4*)(featT + ((size_t)b*N_ + n)*CIN_);
      char* xr = (char*)Xs + rl*256;
      u32 swz = (u32)((rl&7)<<4);
      uint4 v0=fp[t*2], v1=fp[t*2+1];
      *(uint4*)(xr + ((t*32)    ^ swz)) = v0;
      *(uint4*)(xr + ((t*32+16) ^ swz)) = v1;
      uint4 pz = make_uint4(0u,0u,0u,0u);
      if (t==0){
        const float* cp = nxyz + (size_t)bm*3;
        const float* xp = xyz + ((size_t)b*N_ + n)*3;
        u32 w01 = (u32)f2bf(xp[0]-cp[0]) | ((u32)f2bf(xp[1]-cp[1])<<16);
        u32 w2  = (u32)f2bf(xp[2]-cp[2]);
        pz.x = w01; pz.y = w2;
      }
      *(uint4*)(xr + ((128+t*16) ^ swz)) = pz;
    }
    __syncthreads();
    f32x4 acc[4];
    #pragma unroll
    for (int tn=0;tn<4;tn++){ acc[tn][0]=0.f; acc[tn][1]=0.f; acc[tn][2]=0.f; acc[tn][3]=0.f; }
    int arow = w*16 + (lane&15);
    u32 aswz = (u32)((arow&7)<<4);
    #pragma unroll
    for (int k0=0;k0<3;k0++){
      int aoff = arow*256 + (int)(((u32)((k0*32 + ((lane>>4)&3)*8)*2)) ^ aswz);
      bf16x8 a = *(const bf16x8*)((const char*)Xs + aoff);
      #pragma unroll
      for (int tn=0;tn<4;tn++){
        bf16x8 bl = *(const bf16x8*)&WL[((tn*3+k0)*64+lane)*8];
        bf16x8 bh = *(const bf16x8*)&WH[((tn*3+k0)*64+lane)*8];
        acc[tn] = __builtin_amdgcn_mfma_f32_16x16x32_bf16(a, bl, acc[tn], 0,0,0);
        acc[tn] = __builtin_amdgcn_mfma_f32_16x16x32_bf16(a, bh, acc[tn], 0,0,0);
      }
    }
    #pragma unroll
    for (int tn=0;tn<4;tn++){
      int col = tn*16 + (lane&15);
      float bb = bias0[col];
      #pragma unroll
      for (int j=0;j<4;j++){
        int row = w*16 + (lane>>4)*4 + j;
        u16 yb = f2bf(acc[tn][j] + bb);
        Y0[(base+row)*64 + col] = yb;
        float yv = bf2f(yb);
        sSum[tn]+=yv; sSq[tn]+=yv*yv;
      }
    }
    __syncthreads();   // protect Xs before next stage
  }
  #pragma unroll
  for (int tn=0;tn<4;tn++){
    int col = tn*16 + (lane&15);
    atomicAdd(&cs[col],    sSum[tn]);
    atomicAdd(&cs[64+col], sSq[tn]);
  }
  __syncthreads();
  if (tid<64){
    atomicAdd(&stats0[tid*2],   cs[tid]);
    atomicAdd(&stats0[tid*2+1], cs[64+tid]);
  }
}

// ---------------------------------------------------------------- layer 1: MFMA (in-place) + fused stats
__global__ __launch_bounds__(256) void k_mm1(u16* __restrict__ Y,
                                             const u16* __restrict__ Wb1h, const u16* __restrict__ Wb1l,
                                             const float* __restrict__ bias1, const float* __restrict__ gf0,
                                             const float* __restrict__ btf0, const float* __restrict__ stats0,
                                             float* __restrict__ stats1)
{
  __shared__ u16 Xs[64*64];      // 8KB, swizzled
  __shared__ u16 WH[8*64*8];     // 8KB  [tn*2+k0][lane][e]
  __shared__ u16 WL[8*64*8];     // 8KB
  __shared__ float sc[64], sh[64];
  __shared__ float cs[128];
  int tid=threadIdx.x;
  if (tid<64){
    float mu = stats0[tid*2]*INV_ROWS;
    float var= stats0[tid*2+1]*INV_ROWS - mu*mu;
    float rs = 1.0f/sqrtf(var+EPSF);
    float s  = rs*gf0[tid];
    sc[tid]=s; sh[tid]=btf0[tid]-mu*s;
  }
  {
    const uint4* sh4=(const uint4*)Wb1h; uint4* dh4=(uint4*)WH;
    const uint4* sl4=(const uint4*)Wb1l; uint4* dl4=(uint4*)WL;
    dh4[tid]=sh4[tid]; dh4[tid+256]=sh4[tid+256];
    dl4[tid]=sl4[tid]; dl4[tid+256]=sl4[tid+256];
  }
  for (int i=tid;i<128;i+=256) cs[i]=0.f;
  int w=tid>>6, lane=tid&63;
  float sSum[4]={0.f,0.f,0.f,0.f}, sSq[4]={0.f,0.f,0.f,0.f};
  __syncthreads();
  for (int tile=blockIdx.x; tile<8192; tile+=gridDim.x){
    size_t base=(size_t)tile*64;
    for (int i=tid;i<512;i+=256){
      int rl=i>>3, c0=(i&7)*8;
      uint4 v=*(const uint4*)(Y + (base+rl)*64 + c0);
      u32 arr[4]={v.x,v.y,v.z,v.w};
      u32 pk[4];
      #pragma unroll
      for (int q=0;q<4;q++){
        int cc=c0+q*2;
        float lo=bf2f((u16)(arr[q]&0xFFFFu));
        float hi=bf2f((u16)(arr[q]>>16));
        lo=fmaxf(0.f, lo*sc[cc]+sh[cc]);
        hi=fmaxf(0.f, hi*sc[cc+1]+sh[cc+1]);
        pk[q] = (u32)f2bf(lo) | ((u32)f2bf(hi)<<16);
      }
      uint4 o4; o4.x=pk[0]; o4.y=pk[1]; o4.z=pk[2]; o4.w=pk[3];
      int byteoff = rl*128 + ((c0*2) ^ ((rl&7)<<4));
      *(uint4*)((char*)Xs + byteoff) = o4;
    }
    __syncthreads();
    f32x4 acc[4];
    #pragma unroll
    for (int tn=0;tn<4;tn++){ acc[tn][0]=0.f; acc[tn][1]=0.f; acc[tn][2]=0.f; acc[tn][3]=0.f; }
    int arow = w*16 + (lane&15);
    #pragma unroll
    for (int k0=0;k0<2;k0++){
      int aoff = arow*128 + ((k0*64 + (lane>>4)*16) ^ ((arow&7)<<4));
      bf16x8 a = *(const bf16x8*)((const char*)Xs + aoff);
      #pragma unroll
      for (int tn=0;tn<4;tn++){
        bf16x8 bl = *(const bf16x8*)&WL[((tn*2+k0)*64+lane)*8];
        bf16x8 bh = *(const bf16x8*)&WH[((tn*2+k0)*64+lane)*8];
        acc[tn] = __builtin_amdgcn_mfma_f32_16x16x32_bf16(a, bl, acc[tn], 0,0,0);
        acc[tn] = __builtin_amdgcn_mfma_f32_16x16x32_bf16(a, bh, acc[tn], 0,0,0);
      }
    }
    #pragma unroll
    for (int tn=0;tn<4;tn++){
      int col = tn*16 + (lane&15);
      float bb = bias1[col];
      #pragma unroll
      for (int j=0;j<4;j++){
        int row = w*16 + (lane>>4)*4 + j;
        u16 yb = f2bf(acc[tn][j] + bb);
        Y[(base+row)*64 + col] = yb;
        float yv = bf2f(yb);
        sSum[tn]+=yv; sSq[tn]+=yv*yv;
      }
    }
    __syncthreads();   // protect Xs before next stage (in-place read of own tile done)
  }
  #pragma unroll
  for (int tn=0;tn<4;tn++){
    int col = tn*16 + (lane&15);
    atomicAdd(&cs[col],    sSum[tn]);
    atomicAdd(&cs[64+col], sSq[tn]);
  }
  __syncthreads();
  if (tid<64){
    atomicAdd(&stats1[tid*2],   cs[tid]);
    atomicAdd(&stats1[tid*2+1], cs[64+tid]);
  }
}

// ---------------------------------------------------------------- layer 2: MFMA + stats + RAW maxpool (proven R6)
__global__ __launch_bounds__(256) void k_mm2a(const u16* __restrict__ Y1,
                                              const u16* __restrict__ Wb2h, const u16* __restrict__ Wb2l,
                                              const float* __restrict__ bias2, const float* __restrict__ gf1,
                                              const float* __restrict__ btf1, const float* __restrict__ stats1,
                                              float* __restrict__ stats2, float* __restrict__ out1)
{
  __shared__ u16 Xs[64*64];       // 8KB swizzled bf16 (row stride 128B)
  __shared__ u16 WH[8192];        // 16KB [tn*2+k0][lane][e], tn 0..7
  __shared__ u16 WL[8192];        // 16KB
  __shared__ float Ys[64*128];    // 32KB raw y, swizzled (row stride 512B)
  __shared__ float sc[64], sh[64];
  __shared__ float sred[512];
  int tid=threadIdx.x;
  if (tid<64){
    float mu = stats1[tid*2]*INV_ROWS;
    float var= stats1[tid*2+1]*INV_ROWS - mu*mu;
    float rs = 1.0f/sqrtf(var+EPSF);
    float s  = rs*gf1[tid];
    sc[tid]=s; sh[tid]=btf1[tid]-mu*s;
  }
  {
    const uint4* s4=(const uint4*)Wb2h; uint4* d4=(uint4*)WH;
    const uint4* s5=(const uint4*)Wb2l; uint4* d5=(uint4*)WL;
    for (int i=tid;i<1024;i+=256){ d4[i]=s4[i]; d5[i]=s5[i]; }
  }
  int w=tid>>6, lane=tid&63;
  int pg=tid>>7, po=tid&127;      // pool assignment: group (0,1), channel
  float accSum=0.f, accSq=0.f;    // per-thread channel stats across tiles
  __syncthreads();
  for (int tile=blockIdx.x; tile<8192; tile+=gridDim.x){
    size_t base=(size_t)tile*64;
    for (int i=tid;i<512;i+=256){
      int rl=i>>3, c0=(i&7)*8;
      uint4 v=*(const uint4*)(Y1 + (base+rl)*64 + c0);
      u32 arr[4]={v.x,v.y,v.z,v.w};
      u32 pk[4];
      #pragma unroll
      for (int q=0;q<4;q++){
        int cc=c0+q*2;
        float lo=bf2f((u16)(arr[q]&0xFFFFu));
        float hi=bf2f((u16)(arr[q]>>16));
        lo=fmaxf(0.f, lo*sc[cc]+sh[cc]);
        hi=fmaxf(0.f, hi*sc[cc+1]+sh[cc+1]);
        pk[q] = (u32)f2bf(lo) | ((u32)f2bf(hi)<<16);
      }
      uint4 o4; o4.x=pk[0]; o4.y=pk[1]; o4.z=pk[2]; o4.w=pk[3];
      int byteoff = rl*128 + ((c0*2) ^ ((rl&7)<<4));
      *(uint4*)((char*)Xs + byteoff) = o4;
    }
    __syncthreads();
    f32x4 acc[8];
    #pragma unroll
    for (int tn=0;tn<8;tn++){ acc[tn][0]=0.f; acc[tn][1]=0.f; acc[tn][2]=0.f; acc[tn][3]=0.f; }
    int arow = w*16 + (lane&15);
    #pragma unroll
    for (int k0=0;k0<2;k0++){
      int aoff = arow*128 + ((k0*64 + (lane>>4)*16) ^ ((arow&7)<<4));
      bf16x8 a = *(const bf16x8*)((const char*)Xs + aoff);
      #pragma unroll
      for (int tn=0;tn<8;tn++){
        bf16x8 bl = *(const bf16x8*)&WL[((tn*2+k0)*64+lane)*8];
        bf16x8 bh = *(const bf16x8*)&WH[((tn*2+k0)*64+lane)*8];
        acc[tn] = __builtin_amdgcn_mfma_f32_16x16x32_bf16(a, bl, acc[tn], 0,0,0);
        acc[tn] = __builtin_amdgcn_mfma_f32_16x16x32_bf16(a, bh, acc[tn], 0,0,0);
      }
    }
    #pragma unroll
    for (int tn=0;tn<8;tn++){
      int col = tn*16 + (lane&15);
      float bb = bias2[col];
      #pragma unroll
      for (int j=0;j<4;j++){
        int row = w*16 + (lane>>4)*4 + j;
        int byteoff = row*512 + ((col*4) ^ ((row&7)<<4));
        *(float*)((char*)Ys + byteoff) = acc[tn][j] + bb;
      }
    }
    __syncthreads();
    {
      float mx=-3e38f;
      #pragma unroll 4
      for (int k=0;k<32;k++){
        int row = pg*32 + k;
        int byteoff = row*512 + ((po*4) ^ ((row&7)<<4));
        float y = *(const float*)((const char*)Ys + byteoff);
        accSum += y; accSq += y*y;
        mx = fmaxf(mx, y);
      }
      int bm = tile*2 + pg; int bi = bm>>11, m = bm&2047;
      out1[((size_t)bi*128+po)*M_ + m] = mx;
    }
    __syncthreads();   // protect Xs/Ys for next tile
  }
  sred[tid]      = accSum;
  sred[256+tid]  = accSq;
  __syncthreads();
  if (tid<128){
    float s = sred[tid] + sred[tid+128];
    float q = sred[256+tid] + sred[256+tid+128];
    atomicAdd(&stats2[tid*2],   s);
    atomicAdd(&stats2[tid*2+1], q);
  }
}

// ---------------------------------------------------------------- final pool: in-place BN2+ReLU on raw maxes
__global__ __launch_bounds__(256) void k_pool(float* __restrict__ out1, const float* __restrict__ stats2,
                                              const float* __restrict__ gf2, const float* __restrict__ btf2)
{
  int idx = blockIdx.x*256 + threadIdx.x;     // 8*128*2048 = 2097152 elements
  int o = (idx >> 11) & 127;
  float mu = stats2[o*2]*INV_ROWS;
  float var= stats2[o*2+1]*INV_ROWS - mu*mu;
  float rs = 1.0f/sqrtf(var+EPSF);
  float s  = rs*gf2[o];
  float sh = btf2[o]-mu*s;
  out1[idx] = fmaxf(0.f, out1[idx]*s + sh);
}

// ---------------------------------------------------------------- launch
extern "C" void kernel_launch(void* const* d_in, const int* in_sizes, int n_in,
                              void* d_out, int out_size, void* d_ws, size_t ws_size,
                              hipStream_t stream)
{
  (void)in_sizes; (void)n_in; (void)out_size; (void)ws_size;
  const float* xyz =(const float*)d_in[0];
  const float* feat=(const float*)d_in[1];
  const float* w0=(const float*)d_in[2],  *b0=(const float*)d_in[3],  *g0=(const float*)d_in[4],  *bt0=(const float*)d_in[5];
  const float* w1=(const float*)d_in[6],  *b1=(const float*)d_in[7],  *g1=(const float*)d_in[8],  *bt1=(const float*)d_in[9];
  const float* w2=(const float*)d_in[10], *b2=(const float*)d_in[11], *g2=(const float*)d_in[12], *bt2=(const float*)d_in[13];
  float* out0=(float*)d_out;
  float* out1=out0 + (size_t)B_*M_*3;

  char* ws=(char*)d_ws;
  float* nxyz =(float*)(ws);              // 196608 B used
  u16*   Wb1h =(u16*)  (ws + 196608);     // 8192 B
  u16*   Wb1l =(u16*)  (ws + 204800);     // 8192 B
  u16*   Wb2h =(u16*)  (ws + 212992);     // 16384 B
  u16*   Wb2l =(u16*)  (ws + 229376);     // 16384 B (ends 245760 < 262144)
  int*   knn  =(int*)  (ws + 262144);     // 2097152
  u16*   Wb0h =(u16*)  (ws + 2359296);    // 12288 B (reuses dead Wt0 slot)
  u16*   Wb0l =(u16*)  (ws + 2376704);    // 12288 B (reuses dead Wt1 slot)
  float* biasf=(float*)(ws + 2425856);    // 1536
  float* gfp  =(float*)(ws + 2427392);    // 1536
  float* btfp =(float*)(ws + 2428928);    // 1536
  float* stats=(float*)(ws + 2430464);    // 3072
  u16*   featT=(u16*)  (ws + 2433536);    // 8388608
  u16*   Y0   =(u16*)  (ws + 10822144);   // 67108864  (total ~78 MB)

  k_prep<<<1,256,0,stream>>>(w0,b0,g0,bt0,w1,b1,g1,bt1,w2,b2,g2,bt2,biasf,gfp,btfp,stats,
                             Wb0h,Wb0l,Wb1h,Wb1l,Wb2h,Wb2l);
  k_fpstr<<<8+1024,512,0,stream>>>(xyz, nxyz, out0, feat, featT);
  k_bq<<<2048,512,0,stream>>>(xyz, nxyz, knn);
  k_mm0<<<512,256,0,stream>>>(xyz, featT, knn, nxyz, Wb0h, Wb0l, biasf+0, Y0, stats+0);
  k_mm1<<<512,256,0,stream>>>(Y0, Wb1h, Wb1l, biasf+128, gfp+0, btfp+0, stats+0, stats+256);
  k_mm2a<<<512,256,0,stream>>>(Y0, Wb2h, Wb2l, biasf+256, gfp+128, btfp+128, stats+256, stats+512, out1);
  k_pool<<<8192,256,0,stream>>>(out1, stats+512, gfp+256, btfp+256);
}

// Round 13
// 2172.081 us; speedup vs baseline: 1.1572x; 1.0062x over previous
//
#include <hip/hip_runtime.h>
#include <hip/hip_bf16.h>
#include <stdint.h>

typedef unsigned short u16;
typedef unsigned int   u32;
typedef unsigned long long u64;
typedef float v2f __attribute__((ext_vector_type(2)));
typedef __attribute__((ext_vector_type(8))) short bf16x8;
typedef __attribute__((ext_vector_type(4))) float f32x4;

#define B_    8
#define N_    8192
#define M_    2048
#define NS_   32
#define CIN_  64
#define ROWS_ (B_*M_*NS_)          // 524288
#define BIGF  1e10f
#define EPSF  1e-5f
#define INV_ROWS (1.0f/524288.0f)  // 2^-19, exact

__device__ __forceinline__ u16 f2bf(float f){
  u32 x=__float_as_uint(f);
  return (u16)((x + 0x7FFFu + ((x>>16)&1u))>>16);   // RNE
}
__device__ __forceinline__ float bf2f(u16 u){ return __uint_as_float(((u32)u)<<16); }

// DPP full-wave max of non-negative u64 keys; result lands in lane 63.
__device__ __forceinline__ u64 wave_max_key(u64 k){
#define DPP_LVL(CTRL) { \
    u32 lo_=(u32)__builtin_amdgcn_update_dpp(0,(int)(u32)k,(CTRL),0xF,0xF,true); \
    u32 hi_=(u32)__builtin_amdgcn_update_dpp(0,(int)(u32)(k>>32),(CTRL),0xF,0xF,true); \
    u64 o_=((u64)hi_<<32)|(u64)lo_; \
    k=(o_>k)?o_:k; }
  DPP_LVL(0x111)  // row_shr:1
  DPP_LVL(0x112)  // row_shr:2
  DPP_LVL(0x114)  // row_shr:4
  DPP_LVL(0x118)  // row_shr:8
  DPP_LVL(0x142)  // row_bcast:15
  DPP_LVL(0x143)  // row_bcast:31  -> lane 63 holds wave max
#undef DPP_LVL
  return k;
}

// ---------------------------------------------------------------- FPS + transpose + prep (fused, heterogeneous grid)
// Blocks 0..7: R1/R7 measured-best FPS body, frozen (1735us floor).
// Blocks 8..1031: feature transpose riding the idle CUs.
// Block 1032: weight prep (R13: hidden under fps shadow; stream order still
// guarantees completion before mm0 reads stats/fragments).
__global__ __launch_bounds__(512) void k_fpstr(const float* __restrict__ xyz,
                                               float* __restrict__ nxyz, float* __restrict__ out0,
                                               const float* __restrict__ feats, u16* __restrict__ featT,
    const float* w0,const float* b0,const float* g0,const float* bt0,
    const float* w1,const float* b1,const float* g1,const float* bt1,
    const float* w2,const float* b2,const float* g2,const float* bt2,
    float* biasf,float* gf,float* btf,float* stats,
    u16* Wb0h, u16* Wb0l, u16* Wb1h, u16* Wb1l, u16* Wb2h, u16* Wb2l)
{
#pragma clang fp contract(off)
  __shared__ float sx[N_], sy[N_], sz[N_];
  __shared__ int sidx[M_];
  __shared__ u64 skey[2][8];
  int tid=threadIdx.x;
  if (blockIdx.x >= 1032){
    // ---------------- prep part (512 threads); values identical to old k_prep
    for (int i=tid;i<768;i+=512) stats[i]=0.f;
    for (int i=tid;i<6144;i+=512){
      int e=i&7, lane=(i>>3)&63, idx=i>>9;        // idx = tn*3 + k0
      int tn=idx/3, k0=idx%3;
      int col = tn*16 + (lane&15);
      int k   = k0*32 + ((lane>>4)&3)*8 + e;      // 0..95
      float v = 0.f;
      if (k < 64)            v = w0[col*67 + 3 + k];
      else if (k < 67)       v = w0[col*67 + (k-64)];
      u16 hib = f2bf(v);
      Wb0h[i] = hib;
      Wb0l[i] = f2bf(v - bf2f(hib));
    }
    for (int i=tid;i<4096;i+=512){
      int e=i&7, lane=(i>>3)&63, k0=(i>>9)&1, tn=i>>10;
      int col = tn*16 + (lane&15);
      int k   = k0*32 + ((lane>>4)&3)*8 + e;
      float v = w1[col*64 + k];
      u16 hib = f2bf(v);
      Wb1h[i] = hib;
      Wb1l[i] = f2bf(v - bf2f(hib));
    }
    for (int i=tid;i<8192;i+=512){
      int e=i&7, lane=(i>>3)&63, k0=(i>>9)&1, tn=i>>10;
      int col = tn*16 + (lane&15);
      int k   = k0*32 + ((lane>>4)&3)*8 + e;
      float v = w2[col*64 + k];
      u16 hib = f2bf(v);
      Wb2h[i] = hib;
      Wb2l[i] = f2bf(v - bf2f(hib));
    }
    if (tid<64){
      biasf[0*128+tid]=b0[tid]; gf[0*128+tid]=g0[tid]; btf[0*128+tid]=bt0[tid];
      biasf[1*128+tid]=b1[tid]; gf[1*128+tid]=g1[tid]; btf[1*128+tid]=bt1[tid];
    }
    if (tid<128){
      biasf[2*128+tid]=b2[tid]; gf[2*128+tid]=g2[tid]; btf[2*128+tid]=bt2[tid];
    }
    return;
  }
  if (blockIdx.x >= 8){
    // ---------------- transpose part (512 threads; q covers 8 channels of 8)
    float (*t)[65] = (float(*)[65])sx;          // 64*65*4 = 16640B overlay on sx
    int idx = blockIdx.x - 8;                   // 0..1023
    int bb = idx >> 7, n0 = (idx & 127) * 64;
    int a=tid&63, q=tid>>6;                     // q in 0..7
    const float* fp = feats + (size_t)bb*CIN_*N_;
    #pragma unroll
    for (int s=0;s<8;s++){ int c=q*8+s; t[c][a]=fp[(size_t)c*N_ + n0 + a]; }
    __syncthreads();
    u16* op = featT + (size_t)bb*N_*CIN_;
    #pragma unroll
    for (int s=0;s<8;s++){ int n=q*8+s; op[(size_t)(n0+n)*CIN_ + a] = f2bf(t[a][n]); }
    return;
  }
  // ---------------- FPS part (R7 verbatim)
  int b=blockIdx.x;
  const float* xp = xyz + (size_t)b*N_*3;
  for (int i=tid;i<N_;i+=512){ sx[i]=xp[i*3]; sy[i]=xp[i*3+1]; sz[i]=xp[i*3+2]; }
  __syncthreads();
  v2f px[8],py[8],pz[8],md[8];
  int base = tid*16;
  #pragma unroll
  for (int p=0;p<8;p++){
    px[p]=*(const v2f*)&sx[base+2*p];
    py[p]=*(const v2f*)&sy[base+2*p];
    pz[p]=*(const v2f*)&sz[base+2*p];
    v2f m0; m0[0]=BIGF; m0[1]=BIGF; md[p]=m0;
  }
  u32 invb = 0xFFFFFFFFu - (u32)base;
  int far=0;
  int lane=tid&63, wv=tid>>6;
  for (int step=0; step<M_; step++){
    if (tid==0) sidx[step]=far;          // PRE-update emission
    float cxs=sx[far], cys=sy[far], czs=sz[far];
    v2f cx; cx[0]=cxs; cx[1]=cxs;
    v2f cy; cy[0]=cys; cy[1]=cys;
    v2f cz; cz[0]=czs; cz[1]=czs;
    u64 kb=0;
    #pragma unroll
    for (int p=0;p<8;p++){
      v2f dx=px[p]-cx, dy=py[p]-cy, dz=pz[p]-cz;
      v2f d=(dx*dx+dy*dy)+dz*dz;         // contract off: same assoc as ((xx+yy)+zz)
      v2f m=__builtin_elementwise_min(md[p],d);
      md[p]=m;
      u64 k0=((u64)__float_as_uint(m[0])<<32)|(u64)(invb-(u32)(2*p));
      u64 k1=((u64)__float_as_uint(m[1])<<32)|(u64)(invb-(u32)(2*p+1));
      u64 kp=(k1>k0)?k1:k0;              // equal dist -> k0 (lower idx) wins: larger ~idx
      kb=(kp>kb)?kp:kb;
    }
    kb = wave_max_key(kb);
    int par = step & 1;
    if (lane==63) skey[par][wv]=kb;
    __syncthreads();                     // single barrier per step
    u64 a0=skey[par][0],a1=skey[par][1],a2=skey[par][2],a3=skey[par][3];
    u64 a4=skey[par][4],a5=skey[par][5],a6=skey[par][6],a7=skey[par][7];
    a0=(a1>a0)?a1:a0; a2=(a3>a2)?a3:a2; a4=(a5>a4)?a5:a4; a6=(a7>a6)?a7:a6;
    a0=(a2>a0)?a2:a0; a4=(a6>a4)?a6:a4;
    a0=(a4>a0)?a4:a0;
    far = (int)(0xFFFFFFFFu - (u32)(a0 & 0xFFFFFFFFull));
  }
  // f32 output: exact raw coordinates of selected points
  for (int i=tid;i<M_;i+=512){
    int id = sidx[i];
    float x=sx[id], y=sy[id], z=sz[id];
    size_t o=(size_t)(b*M_+i)*3;
    nxyz[o]=x; nxyz[o+1]=y; nxyz[o+2]=z;
    out0[o]=x; out0[o+1]=y; out0[o+2]=z;
  }
}

// ---------------------------------------------------------------- ball query
// R12 destaged (L2-resident xyz). R13: selection via threshold search -- the
// knn ORDER within a centroid is irrelevant (all consumers are k-permutation
// invariant: concat rows, BN sums, max-over-k), only the SET must match the
// reference top-32 by (d, lowest idx). Binary search on distance BITS (uint
// order == float order, d>=0) for theta = 32nd smallest; emit bits<theta then
// bits==theta ties in array order (== index order) -> exact reference set.
// Replaces 32 serial DPP-extract passes (~3200 slots) with ~900.
#define BQCAP 512
__global__ __launch_bounds__(512) void k_bq(const float* __restrict__ xyz, const float* __restrict__ nxyz,
                                            int* __restrict__ knn)
{
  __shared__ float candd[8][BQCAP];
  __shared__ u16  candi[8][BQCAP];
  int tid=threadIdx.x;
  int cid0 = blockIdx.x*8;
  int b = cid0 >> 11;
  const float* xp = xyz + (size_t)b*N_*3;
  int w=tid>>6, lane=tid&63;
  int cid = cid0 + w;
  float cx=nxyz[(size_t)cid*3], cy=nxyz[(size_t)cid*3+1], cz=nxyz[(size_t)cid*3+2];
  float c2 = __fmul_rn(cx,cx);
  c2 = __fadd_rn(c2, __fmul_rn(cy,cy));
  c2 = __fadd_rn(c2, __fmul_rn(cz,cz));
  int cnt=0;
  for (int i0=0;i0<N_;i0+=64){
    int i=i0+lane;
    float x=xp[i*3], y=xp[i*3+1], z=xp[i*3+2];
    float pw = __fmul_rn(x,x);
    pw = __fadd_rn(pw, __fmul_rn(y,y));
    pw = __fadd_rn(pw, __fmul_rn(z,z));
    float dot = __fmul_rn(cx,x);
    dot = __fadd_rn(dot, __fmul_rn(cy,y));
    dot = __fadd_rn(dot, __fmul_rn(cz,z));
    float d2 = __fsub_rn(__fadd_rn(c2,pw), __fmul_rn(2.0f,dot));
    float d = sqrtf(fmaxf(d2,0.f));
    bool in = (d <= 0.4f);
    u64 msk = __ballot(in);
    int pos = cnt + __popcll(msk & ((1ull<<lane)-1ull));
    if (in && pos<BQCAP){ candd[w][pos]=d; candi[w][pos]=(u16)i; }
    cnt += __popcll(msk);
  }
  int R = cnt<BQCAP ? cnt : BQCAP;
  int* kout = knn + (size_t)cid*NS_;
  if (R >= NS_){
    // cache candidate bits in registers (index order preserved); sentinel never selected
    u32 cb[8];
    #pragma unroll
    for (int q=0;q<8;q++){
      int j=lane+q*64;
      cb[q] = (j<R) ? __float_as_uint(candd[w][j]) : 0x7F7FFFFFu;
    }
    // smallest theta with count(bits<=theta) >= NS_  (all real bits < 0x3F000000 = 0.5f)
    u32 lo=0u, hi=0x3F000000u;
    while (lo < hi){
      u32 mid=(lo+hi)>>1;
      int c=0;
      #pragma unroll
      for (int q=0;q<8;q++) c += (int)__popcll(__ballot(cb[q]<=mid));
      if (c >= NS_) hi=mid; else lo=mid+1;
    }
    u32 theta=hi;
    int outPos=0;
    #pragma unroll
    for (int q=0;q<8;q++){
      int j=lane+q*64;
      bool v = (cb[q] < theta);
      u64 mk=__ballot(v);
      int pos = outPos + (int)__popcll(mk & ((1ull<<lane)-1ull));
      if (v) kout[pos]=candi[w][j];
      outPos += (int)__popcll(mk);
    }
    #pragma unroll
    for (int q=0;q<8;q++){
      if (outPos >= NS_) break;          // wave-uniform
      int j=lane+q*64;
      bool v = (cb[q] == theta);
      u64 mk=__ballot(v);
      int pos = outPos + (int)__popcll(mk & ((1ull<<lane)-1ull));
      if (v && pos<NS_) kout[pos]=candi[w][j];
      outPos += (int)__popcll(mk);
    }
  } else {
    if (lane<R) kout[lane]=candi[w][lane];
    int need = NS_-R, slot = R;
    for (int i0=0; i0<N_ && need>0; i0+=64){
      int i=i0+lane;
      float x=xp[i*3], y=xp[i*3+1], z=xp[i*3+2];
      float pw = __fmul_rn(x,x);
      pw = __fadd_rn(pw, __fmul_rn(y,y));
      pw = __fadd_rn(pw, __fmul_rn(z,z));
      float dot = __fmul_rn(cx,x);
      dot = __fadd_rn(dot, __fmul_rn(cy,y));
      dot = __fadd_rn(dot, __fmul_rn(cz,z));
      float d2 = __fsub_rn(__fadd_rn(c2,pw), __fmul_rn(2.0f,dot));
      float d = sqrtf(fmaxf(d2,0.f));
      bool in = (d <= 0.4f);
      u64 mm = __ballot(!in);
      while (mm && need>0){
        int bpos = __ffsll((long long)mm)-1;
        if (lane==0) kout[slot] = i0+bpos;
        slot++; need--;
        mm &= mm-1;
      }
    }
  }
}

// ---------------------------------------------------------------- layer 0: MFMA (gather+concat fused) + fused stats (R12 proven)
__global__ __launch_bounds__(256) void k_mm0(const float* __restrict__ xyz, const u16* __restrict__ featT,
                                             const int* __restrict__ knn, const float* __restrict__ nxyz,
                                             const u16* __restrict__ Wb0h, const u16* __restrict__ Wb0l,
                                             const float* __restrict__ bias0, u16* __restrict__ Y0,
                                             float* __restrict__ stats0)
{
  __shared__ u16 Xs[64*128];     // 16KB, row stride 256B, swizzled
  __shared__ u16 WH[12*64*8];    // 12KB [tn*3+k0][lane][e]
  __shared__ u16 WL[12*64*8];    // 12KB
  __shared__ float cs[128];
  int tid=threadIdx.x;
  {
    const uint4* s4=(const uint4*)Wb0h; uint4* d4=(uint4*)WH;
    const uint4* s5=(const uint4*)Wb0l; uint4* d5=(uint4*)WL;
    for (int i=tid;i<768;i+=256){ d4[i]=s4[i]; d5[i]=s5[i]; }
  }
  for (int i=tid;i<128;i+=256) cs[i]=0.f;
  int w=tid>>6, lane=tid&63;
  int rl=tid>>2, t=tid&3;                 // 4 threads per row (staging)
  float sSum[4]={0.f,0.f,0.f,0.f}, sSq[4]={0.f,0.f,0.f,0.f};
  __syncthreads();
  for (int tile=blockIdx.x; tile<8192; tile+=gridDim.x){
    size_t base=(size_t)tile*64;
    {
      int row=(int)base+rl;
      int bm = row>>5, b = row>>16;
      int n  = knn[row];
      const uint4* fp = (const uint4*)(featT + ((size_t)b*N_ + n)*CIN_);
      char* xr = (char*)Xs + rl*256;
      u32 swz = (u32)((rl&7)<<4);
      uint4 v0=fp[t*2], v1=fp[t*2+1];
      *(uint4*)(xr + ((t*32)    ^ swz)) = v0;
      *(uint4*)(xr + ((t*32+16) ^ swz)) = v1;
      uint4 pz = make_uint4(0u,0u,0u,0u);
      if (t==0){
        const float* cp = nxyz + (size_t)bm*3;
        const float* xp = xyz + ((size_t)b*N_ + n)*3;
        u32 w01 = (u32)f2bf(xp[0]-cp[0]) | ((u32)f2bf(xp[1]-cp[1])<<16);
        u32 w2  = (u32)f2bf(xp[2]-cp[2]);
        pz.x = w01; pz.y = w2;
      }
      *(uint4*)(xr + ((128+t*16) ^ swz)) = pz;
    }
    __syncthreads();
    f32x4 acc[4];
    #pragma unroll
    for (int tn=0;tn<4;tn++){ acc[tn][0]=0.f; acc[tn][1]=0.f; acc[tn][2]=0.f; acc[tn][3]=0.f; }
    int arow = w*16 + (lane&15);
    u32 aswz = (u32)((arow&7)<<4);
    #pragma unroll
    for (int k0=0;k0<3;k0++){
      int aoff = arow*256 + (int)(((u32)((k0*32 + ((lane>>4)&3)*8)*2)) ^ aswz);
      bf16x8 a = *(const bf16x8*)((const char*)Xs + aoff);
      #pragma unroll
      for (int tn=0;tn<4;tn++){
        bf16x8 bl = *(const bf16x8*)&WL[((tn*3+k0)*64+lane)*8];
        bf16x8 bh = *(const bf16x8*)&WH[((tn*3+k0)*64+lane)*8];
        acc[tn] = __builtin_amdgcn_mfma_f32_16x16x32_bf16(a, bl, acc[tn], 0,0,0);
        acc[tn] = __builtin_amdgcn_mfma_f32_16x16x32_bf16(a, bh, acc[tn], 0,0,0);
      }
    }
    #pragma unroll
    for (int tn=0;tn<4;tn++){
      int col = tn*16 + (lane&15);
      float bb = bias0[col];
      #pragma unroll
      for (int j=0;j<4;j++){
        int row = w*16 + (lane>>4)*4 + j;
        u16 yb = f2bf(acc[tn][j] + bb);
        Y0[(base+row)*64 + col] = yb;
        float yv = bf2f(yb);
        sSum[tn]+=yv; sSq[tn]+=yv*yv;
      }
    }
    __syncthreads();   // protect Xs before next stage
  }
  #pragma unroll
  for (int tn=0;tn<4;tn++){
    int col = tn*16 + (lane&15);
    atomicAdd(&cs[col],    sSum[tn]);
    atomicAdd(&cs[64+col], sSq[tn]);
  }
  __syncthreads();
  if (tid<64){
    atomicAdd(&stats0[tid*2],   cs[tid]);
    atomicAdd(&stats0[tid*2+1], cs[64+tid]);
  }
}

// ---------------------------------------------------------------- layer 1: MFMA (in-place) + fused stats (R12 proven)
__global__ __launch_bounds__(256) void k_mm1(u16* __restrict__ Y,
                                             const u16* __restrict__ Wb1h, const u16* __restrict__ Wb1l,
                                             const float* __restrict__ bias1, const float* __restrict__ gf0,
                                             const float* __restrict__ btf0, const float* __restrict__ stats0,
                                             float* __restrict__ stats1)
{
  __shared__ u16 Xs[64*64];      // 8KB, swizzled
  __shared__ u16 WH[8*64*8];     // 8KB  [tn*2+k0][lane][e]
  __shared__ u16 WL[8*64*8];     // 8KB
  __shared__ float sc[64], sh[64];
  __shared__ float cs[128];
  int tid=threadIdx.x;
  if (tid<64){
    float mu = stats0[tid*2]*INV_ROWS;
    float var= stats0[tid*2+1]*INV_ROWS - mu*mu;
    float rs = 1.0f/sqrtf(var+EPSF);
    float s  = rs*gf0[tid];
    sc[tid]=s; sh[tid]=btf0[tid]-mu*s;
  }
  {
    const uint4* sh4=(const uint4*)Wb1h; uint4* dh4=(uint4*)WH;
    const uint4* sl4=(const uint4*)Wb1l; uint4* dl4=(uint4*)WL;
    dh4[tid]=sh4[tid]; dh4[tid+256]=sh4[tid+256];
    dl4[tid]=sl4[tid]; dl4[tid+256]=sl4[tid+256];
  }
  for (int i=tid;i<128;i+=256) cs[i]=0.f;
  int w=tid>>6, lane=tid&63;
  float sSum[4]={0.f,0.f,0.f,0.f}, sSq[4]={0.f,0.f,0.f,0.f};
  __syncthreads();
  for (int tile=blockIdx.x; tile<8192; tile+=gridDim.x){
    size_t base=(size_t)tile*64;
    for (int i=tid;i<512;i+=256){
      int rl=i>>3, c0=(i&7)*8;
      uint4 v=*(const uint4*)(Y + (base+rl)*64 + c0);
      u32 arr[4]={v.x,v.y,v.z,v.w};
      u32 pk[4];
      #pragma unroll
      for (int q=0;q<4;q++){
        int cc=c0+q*2;
        float lo=bf2f((u16)(arr[q]&0xFFFFu));
        float hi=bf2f((u16)(arr[q]>>16));
        lo=fmaxf(0.f, lo*sc[cc]+sh[cc]);
        hi=fmaxf(0.f, hi*sc[cc+1]+sh[cc+1]);
        pk[q] = (u32)f2bf(lo) | ((u32)f2bf(hi)<<16);
      }
      uint4 o4; o4.x=pk[0]; o4.y=pk[1]; o4.z=pk[2]; o4.w=pk[3];
      int byteoff = rl*128 + ((c0*2) ^ ((rl&7)<<4));
      *(uint4*)((char*)Xs + byteoff) = o4;
    }
    __syncthreads();
    f32x4 acc[4];
    #pragma unroll
    for (int tn=0;tn<4;tn++){ acc[tn][0]=0.f; acc[tn][1]=0.f; acc[tn][2]=0.f; acc[tn][3]=0.f; }
    int arow = w*16 + (lane&15);
    #pragma unroll
    for (int k0=0;k0<2;k0++){
      int aoff = arow*128 + ((k0*64 + (lane>>4)*16) ^ ((arow&7)<<4));
      bf16x8 a = *(const bf16x8*)((const char*)Xs + aoff);
      #pragma unroll
      for (int tn=0;tn<4;tn++){
        bf16x8 bl = *(const bf16x8*)&WL[((tn*2+k0)*64+lane)*8];
        bf16x8 bh = *(const bf16x8*)&WH[((tn*2+k0)*64+lane)*8];
        acc[tn] = __builtin_amdgcn_mfma_f32_16x16x32_bf16(a, bl, acc[tn], 0,0,0);
        acc[tn] = __builtin_amdgcn_mfma_f32_16x16x32_bf16(a, bh, acc[tn], 0,0,0);
      }
    }
    #pragma unroll
    for (int tn=0;tn<4;tn++){
      int col = tn*16 + (lane&15);
      float bb = bias1[col];
      #pragma unroll
      for (int j=0;j<4;j++){
        int row = w*16 + (lane>>4)*4 + j;
        u16 yb = f2bf(acc[tn][j] + bb);
        Y[(base+row)*64 + col] = yb;
        float yv = bf2f(yb);
        sSum[tn]+=yv; sSq[tn]+=yv*yv;
      }
    }
    __syncthreads();   // protect Xs before next stage (in-place read of own tile done)
  }
  #pragma unroll
  for (int tn=0;tn<4;tn++){
    int col = tn*16 + (lane&15);
    atomicAdd(&cs[col],    sSum[tn]);
    atomicAdd(&cs[64+col], sSq[tn]);
  }
  __syncthreads();
  if (tid<64){
    atomicAdd(&stats1[tid*2],   cs[tid]);
    atomicAdd(&stats1[tid*2+1], cs[64+tid]);
  }
}

// ---------------------------------------------------------------- layer 2: MFMA + stats + RAW maxpool (proven R6)
__global__ __launch_bounds__(256) void k_mm2a(const u16* __restrict__ Y1,
                                              const u16* __restrict__ Wb2h, const u16* __restrict__ Wb2l,
                                              const float* __restrict__ bias2, const float* __restrict__ gf1,
                                              const float* __restrict__ btf1, const float* __restrict__ stats1,
                                              float* __restrict__ stats2, float* __restrict__ out1)
{
  __shared__ u16 Xs[64*64];       // 8KB swizzled bf16 (row stride 128B)
  __shared__ u16 WH[8192];        // 16KB [tn*2+k0][lane][e], tn 0..7
  __shared__ u16 WL[8192];        // 16KB
  __shared__ float Ys[64*128];    // 32KB raw y, swizzled (row stride 512B)
  __shared__ float sc[64], sh[64];
  __shared__ float sred[512];
  int tid=threadIdx.x;
  if (tid<64){
    float mu = stats1[tid*2]*INV_ROWS;
    float var= stats1[tid*2+1]*INV_ROWS - mu*mu;
    float rs = 1.0f/sqrtf(var+EPSF);
    float s  = rs*gf1[tid];
    sc[tid]=s; sh[tid]=btf1[tid]-mu*s;
  }
  {
    const uint4* s4=(const uint4*)Wb2h; uint4* d4=(uint4*)WH;
    const uint4* s5=(const uint4*)Wb2l; uint4* d5=(uint4*)WL;
    for (int i=tid;i<1024;i+=256){ d4[i]=s4[i]; d5[i]=s5[i]; }
  }
  int w=tid>>6, lane=tid&63;
  int pg=tid>>7, po=tid&127;      // pool assignment: group (0,1), channel
  float accSum=0.f, accSq=0.f;    // per-thread channel stats across tiles
  __syncthreads();
  for (int tile=blockIdx.x; tile<8192; tile+=gridDim.x){
    size_t base=(size_t)tile*64;
    for (int i=tid;i<512;i+=256){
      int rl=i>>3, c0=(i&7)*8;
      uint4 v=*(const uint4*)(Y1 + (base+rl)*64 + c0);
      u32 arr[4]={v.x,v.y,v.z,v.w};
      u32 pk[4];
      #pragma unroll
      for (int q=0;q<4;q++){
        int cc=c0+q*2;
        float lo=bf2f((u16)(arr[q]&0xFFFFu));
        float hi=bf2f((u16)(arr[q]>>16));
        lo=fmaxf(0.f, lo*sc[cc]+sh[cc]);
        hi=fmaxf(0.f, hi*sc[cc+1]+sh[cc+1]);
        pk[q] = (u32)f2bf(lo) | ((u32)f2bf(hi)<<16);
      }
      uint4 o4; o4.x=pk[0]; o4.y=pk[1]; o4.z=pk[2]; o4.w=pk[3];
      int byteoff = rl*128 + ((c0*2) ^ ((rl&7)<<4));
      *(uint4*)((char*)Xs + byteoff) = o4;
    }
    __syncthreads();
    f32x4 acc[8];
    #pragma unroll
    for (int tn=0;tn<8;tn++){ acc[tn][0]=0.f; acc[tn][1]=0.f; acc[tn][2]=0.f; acc[tn][3]=0.f; }
    int arow = w*16 + (lane&15);
    #pragma unroll
    for (int k0=0;k0<2;k0++){
      int aoff = arow*128 + ((k0*64 + (lane>>4)*16) ^ ((arow&7)<<4));
      bf16x8 a = *(const bf16x8*)((const char*)Xs + aoff);
      #pragma unroll
      for (int tn=0;tn<8;tn++){
        bf16x8 bl = *(const bf16x8*)&WL[((tn*2+k0)*64+lane)*8];
        bf16x8 bh = *(const bf16x8*)&WH[((tn*2+k0)*64+lane)*8];
        acc[tn] = __builtin_amdgcn_mfma_f32_16x16x32_bf16(a, bl, acc[tn], 0,0,0);
        acc[tn] = __builtin_amdgcn_mfma_f32_16x16x32_bf16(a, bh, acc[tn], 0,0,0);
      }
    }
    #pragma unroll
    for (int tn=0;tn<8;tn++){
      int col = tn*16 + (lane&15);
      float bb = bias2[col];
      #pragma unroll
      for (int j=0;j<4;j++){
        int row = w*16 + (lane>>4)*4 + j;
        int byteoff = row*512 + ((col*4) ^ ((row&7)<<4));
        *(float*)((char*)Ys + byteoff) = acc[tn][j] + bb;
      }
    }
    __syncthreads();
    {
      float mx=-3e38f;
      #pragma unroll 4
      for (int k=0;k<32;k++){
        int row = pg*32 + k;
        int byteoff = row*512 + ((po*4) ^ ((row&7)<<4));
        float y = *(const float*)((const char*)Ys + byteoff);
        accSum += y; accSq += y*y;
        mx = fmaxf(mx, y);
      }
      int bm = tile*2 + pg; int bi = bm>>11, m = bm&2047;
      out1[((size_t)bi*128+po)*M_ + m] = mx;
    }
    __syncthreads();   // protect Xs/Ys for next tile
  }
  sred[tid]      = accSum;
  sred[256+tid]  = accSq;
  __syncthreads();
  if (tid<128){
    float s = sred[tid] + sred[tid+128];
    float q = sred[256+tid] + sred[256+tid+128];
    atomicAdd(&stats2[tid*2],   s);
    atomicAdd(&stats2[tid*2+1], q);
  }
}

// ---------------------------------------------------------------- final pool: in-place BN2+ReLU, float4 (R13)
__global__ __launch_bounds__(256) void k_pool(float* __restrict__ out1, const float* __restrict__ stats2,
                                              const float* __restrict__ gf2, const float* __restrict__ btf2)
{
  int idx4 = blockIdx.x*256 + threadIdx.x;    // 524288 float4 = 2097152 floats
  int o = (idx4 >> 9) & 127;                  // 512 float4 per (batch,channel) row
  float mu = stats2[o*2]*INV_ROWS;
  float var= stats2[o*2+1]*INV_ROWS - mu*mu;
  float rs = 1.0f/sqrtf(var+EPSF);
  float s  = rs*gf2[o];
  float sh = btf2[o]-mu*s;
  float4 v = ((const float4*)out1)[idx4];
  v.x=fmaxf(0.f, v.x*s+sh);
  v.y=fmaxf(0.f, v.y*s+sh);
  v.z=fmaxf(0.f, v.z*s+sh);
  v.w=fmaxf(0.f, v.w*s+sh);
  ((float4*)out1)[idx4]=v;
}

// ---------------------------------------------------------------- launch
extern "C" void kernel_launch(void* const* d_in, const int* in_sizes, int n_in,
                              void* d_out, int out_size, void* d_ws, size_t ws_size,
                              hipStream_t stream)
{
  (void)in_sizes; (void)n_in; (void)out_size; (void)ws_size;
  const float* xyz =(const float*)d_in[0];
  const float* feat=(const float*)d_in[1];
  const float* w0=(const float*)d_in[2],  *b0=(const float*)d_in[3],  *g0=(const float*)d_in[4],  *bt0=(const float*)d_in[5];
  const float* w1=(const float*)d_in[6],  *b1=(const float*)d_in[7],  *g1=(const float*)d_in[8],  *bt1=(const float*)d_in[9];
  const float* w2=(const float*)d_in[10], *b2=(const float*)d_in[11], *g2=(const float*)d_in[12], *bt2=(const float*)d_in[13];
  float* out0=(float*)d_out;
  float* out1=out0 + (size_t)B_*M_*3;

  char* ws=(char*)d_ws;
  float* nxyz =(float*)(ws);              // 196608 B used
  u16*   Wb1h =(u16*)  (ws + 196608);     // 8192 B
  u16*   Wb1l =(u16*)  (ws + 204800);     // 8192 B
  u16*   Wb2h =(u16*)  (ws + 212992);     // 16384 B
  u16*   Wb2l =(u16*)  (ws + 229376);     // 16384 B (ends 245760 < 262144)
  int*   knn  =(int*)  (ws + 262144);     // 2097152
  u16*   Wb0h =(u16*)  (ws + 2359296);    // 12288 B (reuses dead Wt0 slot)
  u16*   Wb0l =(u16*)  (ws + 2376704);    // 12288 B (reuses dead Wt1 slot)
  float* biasf=(float*)(ws + 2425856);    // 1536
  float* gfp  =(float*)(ws + 2427392);    // 1536
  float* btfp =(float*)(ws + 2428928);    // 1536
  float* stats=(float*)(ws + 2430464);    // 3072
  u16*   featT=(u16*)  (ws + 2433536);    // 8388608
  u16*   Y0   =(u16*)  (ws + 10822144);   // 67108864  (total ~78 MB)

  k_fpstr<<<8+1024+1,512,0,stream>>>(xyz, nxyz, out0, feat, featT,
                                     w0,b0,g0,bt0,w1,b1,g1,bt1,w2,b2,g2,bt2,
                                     biasf,gfp,btfp,stats,
                                     Wb0h,Wb0l,Wb1h,Wb1l,Wb2h,Wb2l);
  k_bq<<<2048,512,0,stream>>>(xyz, nxyz, knn);
  k_mm0<<<512,256,0,stream>>>(xyz, featT, knn, nxyz, Wb0h, Wb0l, biasf+0, Y0, stats+0);
  k_mm1<<<512,256,0,stream>>>(Y0, Wb1h, Wb1l, biasf+128, gfp+0, btfp+0, stats+0, stats+256);
  k_mm2a<<<512,256,0,stream>>>(Y0, Wb2h, Wb2l, biasf+256, gfp+128, btfp+128, stats+256, stats+512, out1);
  k_pool<<<2048,256,0,stream>>>(out1, stats+512, gfp+256, btfp+256);
}